// Round 1
// baseline (7210.675 us; speedup 1.0000x reference)
//
#include <hip/hip_runtime.h>

#define SLOPE 0.01f

__device__ __forceinline__ float lrelu(float v) { return v >= 0.0f ? v : SLOPE * v; }

// ---------------- degree ----------------
__global__ __launch_bounds__(256) void deg_accum(const int* __restrict__ cols,
                                                 float* __restrict__ deg, int E) {
  int t = blockIdx.x * 256 + threadIdx.x;
  if (t < E) atomicAdd(&deg[cols[t]], 1.0f);
}

__global__ __launch_bounds__(256) void deg_finish(float* __restrict__ deg, int n) {
  int t = blockIdx.x * 256 + threadIdx.x;
  if (t < n) deg[t] = 1.0f / sqrtf(deg[t] + 1.0f);
}

// ---------------- GEMM: y = f((x @ W) [+bias] [*rowscale]) ----------------
// 64 rows per block, W staged in 32-row K-panels, per-thread tile RPT x 8.
template<int K, int C, bool ACT, bool SCALE, bool BIAS>
__global__ __launch_bounds__(256) void gemm_kernel(
    const float* __restrict__ x, const float* __restrict__ W,
    const float* __restrict__ bias, const float* __restrict__ rowscale,
    float* __restrict__ y, int n)
{
  constexpr int TC  = C / 8;        // thread-cols (each thread owns 8 cols: two float4 halves)
  constexpr int TR  = 256 / TC;     // thread-rows
  constexpr int RPT = 64 / TR;      // rows per thread
  constexpr int XS  = K + 4;        // padded LDS stride (keeps 16B align, shifts banks per row)
  __shared__ float xs[64 * XS];
  __shared__ float ws[32 * C];
  const int t = threadIdx.x;
  const int row0 = blockIdx.x * 64;

  // stage x tile (64 x K)
  for (int i = t; i < 64 * (K / 4); i += 256) {
    int r  = i / (K / 4);
    int kk = (i % (K / 4)) * 4;
    int rg = row0 + r;
    float4 v = make_float4(0.f, 0.f, 0.f, 0.f);
    if (rg < n) v = *(const float4*)(x + (size_t)rg * K + kk);
    float* dst = &xs[r * XS + kk];
    dst[0] = v.x; dst[1] = v.y; dst[2] = v.z; dst[3] = v.w;
  }

  const int tc = t % TC, tr = t / TC;
  const int c0 = tc * 4, c1 = C / 2 + tc * 4;
  const int rb = tr * RPT;

  float acc[RPT][8];
  #pragma unroll
  for (int i = 0; i < RPT; ++i)
    #pragma unroll
    for (int j = 0; j < 8; ++j) acc[i][j] = 0.f;

  for (int kp = 0; kp < K; kp += 32) {
    __syncthreads();
    // stage W panel (32 x C)
    for (int i = t; i < 32 * C / 4; i += 256)
      ((float4*)ws)[i] = ((const float4*)(W + (size_t)kp * C))[i];
    __syncthreads();

    for (int k = 0; k < 32; k += 4) {
      float xv[RPT][4];
      #pragma unroll
      for (int i = 0; i < RPT; ++i) {
        float4 tmp = *(const float4*)&xs[(rb + i) * XS + kp + k];
        xv[i][0] = tmp.x; xv[i][1] = tmp.y; xv[i][2] = tmp.z; xv[i][3] = tmp.w;
      }
      #pragma unroll
      for (int kk = 0; kk < 4; ++kk) {
        float4 w0 = *(const float4*)&ws[(k + kk) * C + c0];
        float4 w1 = *(const float4*)&ws[(k + kk) * C + c1];
        float wv[8] = {w0.x, w0.y, w0.z, w0.w, w1.x, w1.y, w1.z, w1.w};
        #pragma unroll
        for (int i = 0; i < RPT; ++i) {
          float xk = xv[i][kk];
          #pragma unroll
          for (int j = 0; j < 8; ++j) acc[i][j] = fmaf(xk, wv[j], acc[i][j]);
        }
      }
    }
  }

  float b[8];
  if (BIAS) {
    float4 b0 = *(const float4*)(bias + c0);
    float4 b1 = *(const float4*)(bias + c1);
    b[0] = b0.x; b[1] = b0.y; b[2] = b0.z; b[3] = b0.w;
    b[4] = b1.x; b[5] = b1.y; b[6] = b1.z; b[7] = b1.w;
  }
  #pragma unroll
  for (int i = 0; i < RPT; ++i) {
    int rg = row0 + rb + i;
    if (rg >= n) continue;
    float sc = SCALE ? rowscale[rg] : 1.0f;
    float o[8];
    #pragma unroll
    for (int j = 0; j < 8; ++j) {
      float v = acc[i][j];
      if (BIAS) v += b[j];
      if (SCALE) v *= sc;
      if (ACT) v = lrelu(v);
      o[j] = v;
    }
    *(float4*)(y + (size_t)rg * C + c0) = make_float4(o[0], o[1], o[2], o[3]);
    *(float4*)(y + (size_t)rg * C + c1) = make_float4(o[4], o[5], o[6], o[7]);
  }
}

// ---------------- edge scatter: agg[col] += hs[row] ----------------
template<int C>
__global__ __launch_bounds__(256) void scatter_kernel(
    const int* __restrict__ rows, const int* __restrict__ cols,
    const float* __restrict__ hs, float* __restrict__ agg, int E)
{
  constexpr int CH = C / 4;
  long long t = (long long)blockIdx.x * 256 + threadIdx.x;
  int e = (int)(t / CH);
  int c = (int)(t % CH);
  if (e >= E) return;
  int r  = rows[e];
  int cc = cols[e];
  const float4 h = *(const float4*)(hs + (size_t)r * C + c * 4);
  float* dst = agg + (size_t)cc * C + c * 4;
  atomicAdd(dst + 0, h.x);
  atomicAdd(dst + 1, h.y);
  atomicAdd(dst + 2, h.z);
  atomicAdd(dst + 3, h.w);
}

// ---------------- finalize: y = lrelu(dis*(agg+hs) + b) ----------------
template<int C>
__global__ __launch_bounds__(256) void finalize_kernel(
    const float* __restrict__ agg, const float* __restrict__ hs,
    const float* __restrict__ dis, const float* __restrict__ bias,
    float* __restrict__ y, int n)
{
  constexpr int CH = C / 4;
  long long t = (long long)blockIdx.x * 256 + threadIdx.x;
  int node = (int)(t / CH), c = (int)(t % CH);
  if (node >= n) return;
  float d = dis[node];
  size_t off = (size_t)node * C + c * 4;
  float4 a  = *(const float4*)(agg + off);
  float4 h  = *(const float4*)(hs + off);
  float4 b4 = *(const float4*)(bias + c * 4);
  float4 o;
  o.x = lrelu((a.x + h.x) * d + b4.x);
  o.y = lrelu((a.y + h.y) * d + b4.y);
  o.z = lrelu((a.z + h.z) * d + b4.z);
  o.w = lrelu((a.w + h.w) * d + b4.w);
  *(float4*)(y + off) = o;
}

// ---------------- conv3 finalize + mean (C=64), no materialized output ----------------
__global__ __launch_bounds__(256) void finalize_mean64(
    const float* __restrict__ agg, const float* __restrict__ hs,
    const float* __restrict__ dis, const float* __restrict__ bias,
    float* __restrict__ out, int n)
{
  const int t = threadIdx.x;
  const int c = t & 15;         // float4 chunk (16 chunks of 4 = 64 cols)
  const int nl = t >> 4;        // 0..15
  const int base = blockIdx.x * 128;
  float4 b4 = *(const float4*)(bias + c * 4);
  float4 sum = make_float4(0.f, 0.f, 0.f, 0.f);
  #pragma unroll
  for (int g = 0; g < 8; ++g) {
    int node = base + g * 16 + nl;
    if (node < n) {
      float d = dis[node];
      size_t off = (size_t)node * 64 + c * 4;
      float4 a = *(const float4*)(agg + off);
      float4 h = *(const float4*)(hs + off);
      sum.x += lrelu((a.x + h.x) * d + b4.x);
      sum.y += lrelu((a.y + h.y) * d + b4.y);
      sum.z += lrelu((a.z + h.z) * d + b4.z);
      sum.w += lrelu((a.w + h.w) * d + b4.w);
    }
  }
  __shared__ float4 s[256];
  s[t] = sum;
  __syncthreads();
  for (int off = 128; off >= 16; off >>= 1) {
    if (t < off) {
      s[t].x += s[t + off].x; s[t].y += s[t + off].y;
      s[t].z += s[t + off].z; s[t].w += s[t + off].w;
    }
    __syncthreads();
  }
  if (t < 16) {
    const float inv = 1.0f / (float)n;
    atomicAdd(out + t * 4 + 0, s[t].x * inv);
    atomicAdd(out + t * 4 + 1, s[t].y * inv);
    atomicAdd(out + t * 4 + 2, s[t].z * inv);
    atomicAdd(out + t * 4 + 3, s[t].w * inv);
  }
}

extern "C" void kernel_launch(void* const* d_in, const int* in_sizes, int n_in,
                              void* d_out, int out_size, void* d_ws, size_t ws_size,
                              hipStream_t stream) {
  const float* pose = (const float*)d_in[0];
  const float* w_pos = (const float*)d_in[1];
  const float* b_pos = (const float*)d_in[2];
  const float* w_fc  = (const float*)d_in[3];
  const float* b_fc  = (const float*)d_in[4];
  const float* w_g1  = (const float*)d_in[5];
  const float* b_g1  = (const float*)d_in[6];
  const float* w_g2  = (const float*)d_in[7];
  const float* b_g2  = (const float*)d_in[8];
  const float* w_g3  = (const float*)d_in[9];
  const float* b_g3  = (const float*)d_in[10];
  const int*   edges = (const int*)d_in[11];

  const int n = in_sizes[0] / 64;       // N_NODES
  const int E = in_sizes[11] / 2;       // N_EDGES
  const int* rows = edges;
  const int* cols = edges + E;

  float* dis  = (float*)d_ws;
  float* bufA = (float*)((char*)d_ws + (1 << 19));
  float* bufB = (float*)((char*)d_ws + (1 << 19) + (size_t)n * 128 * 4);

  const int gemm_blocks = (n + 63) / 64;
  const int e_blocks    = (E + 255) / 256;
  const int n_blocks    = (n + 255) / 256;
  const int sc128_blocks = (int)(((long long)E * 32 + 255) / 256);
  const int sc64_blocks  = (int)(((long long)E * 16 + 255) / 256);
  const int fin128_blocks = (int)(((long long)n * 32 + 255) / 256);
  const int fm_blocks = (n + 127) / 128;

  // degrees -> dis = 1/sqrt(deg+1)
  hipMemsetAsync(dis, 0, (size_t)n * 4, stream);
  deg_accum<<<e_blocks, 256, 0, stream>>>(cols, dis, E);
  deg_finish<<<n_blocks, 256, 0, stream>>>(dis, n);

  // refine: x1 = lrelu(pose @ w_pos + b_pos) ; x2 = x1 @ w_fc + b_fc
  gemm_kernel<64, 128, true, false, true><<<gemm_blocks, 256, 0, stream>>>(
      pose, w_pos, b_pos, nullptr, bufA, n);
  gemm_kernel<128, 128, false, false, true><<<gemm_blocks, 256, 0, stream>>>(
      bufA, w_fc, b_fc, nullptr, bufB, n);

  // conv1: hs = (x2 @ w_g1) * dis   (bufB -> bufA)
  gemm_kernel<128, 128, false, true, false><<<gemm_blocks, 256, 0, stream>>>(
      bufB, w_g1, nullptr, dis, bufA, n);
  hipMemsetAsync(bufB, 0, (size_t)n * 128 * 4, stream);
  scatter_kernel<128><<<sc128_blocks, 256, 0, stream>>>(rows, cols, bufA, bufB, E);
  finalize_kernel<128><<<fin128_blocks, 256, 0, stream>>>(bufB, bufA, dis, b_g1, bufB, n);

  // conv2
  gemm_kernel<128, 128, false, true, false><<<gemm_blocks, 256, 0, stream>>>(
      bufB, w_g2, nullptr, dis, bufA, n);
  hipMemsetAsync(bufB, 0, (size_t)n * 128 * 4, stream);
  scatter_kernel<128><<<sc128_blocks, 256, 0, stream>>>(rows, cols, bufA, bufB, E);
  finalize_kernel<128><<<fin128_blocks, 256, 0, stream>>>(bufB, bufA, dis, b_g2, bufB, n);

  // conv3 (C=64) + mean
  gemm_kernel<128, 64, false, true, false><<<gemm_blocks, 256, 0, stream>>>(
      bufB, w_g3, nullptr, dis, bufA, n);
  hipMemsetAsync(bufB, 0, (size_t)n * 64 * 4, stream);
  scatter_kernel<64><<<sc64_blocks, 256, 0, stream>>>(rows, cols, bufA, bufB, E);
  hipMemsetAsync(d_out, 0, 64 * 4, stream);
  finalize_mean64<<<fm_blocks, 256, 0, stream>>>(bufB, bufA, dis, b_g3, (float*)d_out, n);
}

// Round 2
// 937.247 us; speedup vs baseline: 7.6935x; 7.6935x over previous
//
#include <hip/hip_runtime.h>

#define SLOPE 0.01f

__device__ __forceinline__ float lrelu(float v) { return v >= 0.0f ? v : SLOPE * v; }

// ---------------- CSR build ----------------
__global__ __launch_bounds__(256) void cnt_accum(const int* __restrict__ cols,
                                                 int* __restrict__ cnt, int E) {
  int t = blockIdx.x * 256 + threadIdx.x;
  if (t < E) atomicAdd(&cnt[cols[t]], 1);
}

// per-block (1024 elems) exclusive scan; also dis = rsqrt(cnt+1)
__global__ __launch_bounds__(256) void scan1(const int* __restrict__ cnt,
                                             int* __restrict__ off,
                                             int* __restrict__ bsums,
                                             float* __restrict__ dis, int n) {
  __shared__ int s[256];
  const int t = threadIdx.x;
  const int base = blockIdx.x * 1024 + t * 4;
  int c[4];
  #pragma unroll
  for (int j = 0; j < 4; ++j) { int i = base + j; c[j] = (i < n) ? cnt[i] : 0; }
  int tsum = c[0] + c[1] + c[2] + c[3];
  s[t] = tsum;
  __syncthreads();
  for (int d = 1; d < 256; d <<= 1) {
    int v = (t >= d) ? s[t - d] : 0;
    __syncthreads();
    s[t] += v;
    __syncthreads();
  }
  int run = s[t] - tsum;  // exclusive prefix within block
  #pragma unroll
  for (int j = 0; j < 4; ++j) {
    int i = base + j;
    if (i < n) { off[i] = run; dis[i] = rsqrtf((float)c[j] + 1.0f); }
    run += c[j];
  }
  if (t == 255) bsums[blockIdx.x] = s[255];
}

// single-block exclusive scan of block sums (nb <= 256)
__global__ __launch_bounds__(256) void scan2(int* __restrict__ bsums, int nb) {
  __shared__ int s[256];
  const int t = threadIdx.x;
  int v = (t < nb) ? bsums[t] : 0;
  s[t] = v;
  __syncthreads();
  for (int d = 1; d < 256; d <<= 1) {
    int u = (t >= d) ? s[t - d] : 0;
    __syncthreads();
    s[t] += u;
    __syncthreads();
  }
  if (t < nb) bsums[t] = s[t] - v;
}

__global__ __launch_bounds__(256) void scan3(int* __restrict__ off,
                                             const int* __restrict__ bsums, int n) {
  int i = blockIdx.x * 256 + threadIdx.x;
  if (i < n) off[i] += bsums[i >> 10];
}

__global__ __launch_bounds__(256) void fill_csr(const int* __restrict__ rows,
                                                const int* __restrict__ cols,
                                                const int* __restrict__ off,
                                                int* __restrict__ cursor,
                                                int* __restrict__ csr, int E) {
  int e = blockIdx.x * 256 + threadIdx.x;
  if (e >= E) return;
  int c = cols[e];
  int p = off[c] + atomicAdd(&cursor[c], 1);
  csr[p] = rows[e];
}

// ---------------- GEMM: y = f((x @ W) [+bias] [*rowscale]) ----------------
template<int K, int C, bool ACT, bool SCALE, bool BIAS>
__global__ __launch_bounds__(256) void gemm_kernel(
    const float* __restrict__ x, const float* __restrict__ W,
    const float* __restrict__ bias, const float* __restrict__ rowscale,
    float* __restrict__ y, int n)
{
  constexpr int TC  = C / 8;
  constexpr int TR  = 256 / TC;
  constexpr int RPT = 64 / TR;
  constexpr int XS  = K + 4;
  __shared__ float xs[64 * XS];
  __shared__ float ws[32 * C];
  const int t = threadIdx.x;
  const int row0 = blockIdx.x * 64;

  for (int i = t; i < 64 * (K / 4); i += 256) {
    int r  = i / (K / 4);
    int kk = (i % (K / 4)) * 4;
    int rg = row0 + r;
    float4 v = make_float4(0.f, 0.f, 0.f, 0.f);
    if (rg < n) v = *(const float4*)(x + (size_t)rg * K + kk);
    float* dst = &xs[r * XS + kk];
    dst[0] = v.x; dst[1] = v.y; dst[2] = v.z; dst[3] = v.w;
  }

  const int tc = t % TC, tr = t / TC;
  const int c0 = tc * 4, c1 = C / 2 + tc * 4;
  const int rb = tr * RPT;

  float acc[RPT][8];
  #pragma unroll
  for (int i = 0; i < RPT; ++i)
    #pragma unroll
    for (int j = 0; j < 8; ++j) acc[i][j] = 0.f;

  for (int kp = 0; kp < K; kp += 32) {
    __syncthreads();
    for (int i = t; i < 32 * C / 4; i += 256)
      ((float4*)ws)[i] = ((const float4*)(W + (size_t)kp * C))[i];
    __syncthreads();

    for (int k = 0; k < 32; k += 4) {
      float xv[RPT][4];
      #pragma unroll
      for (int i = 0; i < RPT; ++i) {
        float4 tmp = *(const float4*)&xs[(rb + i) * XS + kp + k];
        xv[i][0] = tmp.x; xv[i][1] = tmp.y; xv[i][2] = tmp.z; xv[i][3] = tmp.w;
      }
      #pragma unroll
      for (int kk = 0; kk < 4; ++kk) {
        float4 w0 = *(const float4*)&ws[(k + kk) * C + c0];
        float4 w1 = *(const float4*)&ws[(k + kk) * C + c1];
        float wv[8] = {w0.x, w0.y, w0.z, w0.w, w1.x, w1.y, w1.z, w1.w};
        #pragma unroll
        for (int i = 0; i < RPT; ++i) {
          float xk = xv[i][kk];
          #pragma unroll
          for (int j = 0; j < 8; ++j) acc[i][j] = fmaf(xk, wv[j], acc[i][j]);
        }
      }
    }
  }

  float b[8];
  if (BIAS) {
    float4 b0 = *(const float4*)(bias + c0);
    float4 b1 = *(const float4*)(bias + c1);
    b[0] = b0.x; b[1] = b0.y; b[2] = b0.z; b[3] = b0.w;
    b[4] = b1.x; b[5] = b1.y; b[6] = b1.z; b[7] = b1.w;
  }
  #pragma unroll
  for (int i = 0; i < RPT; ++i) {
    int rg = row0 + rb + i;
    if (rg >= n) continue;
    float sc = SCALE ? rowscale[rg] : 1.0f;
    float o[8];
    #pragma unroll
    for (int j = 0; j < 8; ++j) {
      float v = acc[i][j];
      if (BIAS) v += b[j];
      if (SCALE) v *= sc;
      if (ACT) v = lrelu(v);
      o[j] = v;
    }
    *(float4*)(y + (size_t)rg * C + c0) = make_float4(o[0], o[1], o[2], o[3]);
    *(float4*)(y + (size_t)rg * C + c1) = make_float4(o[4], o[5], o[6], o[7]);
  }
}

// ---------------- fused gather + self-loop + bias + lrelu ----------------
// C threads per node; each thread owns one column. Neighbor row reads coalesced.
template<int C>
__global__ __launch_bounds__(256) void gather_kernel(
    const int* __restrict__ csr, const int* __restrict__ off, const int* __restrict__ cnt,
    const float* __restrict__ hs, const float* __restrict__ dis,
    const float* __restrict__ bias, float* __restrict__ y, int n)
{
  constexpr int NPB = 256 / C;
  const int t = threadIdx.x;
  const int col = t & (C - 1);
  const int node = blockIdx.x * NPB + t / C;
  if (node >= n) return;
  const int o = off[node], d = cnt[node];
  float acc = 0.f;
  int j = 0;
  for (; j + 2 <= d; j += 2) {
    int r0 = csr[o + j];
    int r1 = csr[o + j + 1];
    acc += hs[(size_t)r0 * C + col];
    acc += hs[(size_t)r1 * C + col];
  }
  if (j < d) acc += hs[(size_t)csr[o + j] * C + col];
  float v = (acc + hs[(size_t)node * C + col]) * dis[node] + bias[col];
  y[(size_t)node * C + col] = lrelu(v);
}

// ---------------- conv3: gather + finalize + mean (C=64) ----------------
__global__ __launch_bounds__(256) void gather_mean64(
    const int* __restrict__ csr, const int* __restrict__ off, const int* __restrict__ cnt,
    const float* __restrict__ hs, const float* __restrict__ dis,
    const float* __restrict__ bias, float* __restrict__ out, int n)
{
  const int t = threadIdx.x;
  const int col = t & 63;
  const int grp = t >> 6;        // 0..3
  const int NPG = 8;             // nodes per group
  const float b = bias[col];
  float colsum = 0.f;
  const int base = blockIdx.x * 4 * NPG + grp * NPG;
  for (int g = 0; g < NPG; ++g) {
    int node = base + g;
    if (node >= n) break;
    int o = off[node], d = cnt[node];
    float acc = 0.f;
    int j = 0;
    for (; j + 2 <= d; j += 2) {
      int r0 = csr[o + j];
      int r1 = csr[o + j + 1];
      acc += hs[(size_t)r0 * 64 + col];
      acc += hs[(size_t)r1 * 64 + col];
    }
    if (j < d) acc += hs[(size_t)csr[o + j] * 64 + col];
    colsum += lrelu((acc + hs[(size_t)node * 64 + col]) * dis[node] + b);
  }
  __shared__ float s[256];
  s[t] = colsum;
  __syncthreads();
  if (t < 128) s[t] += s[t + 128];
  __syncthreads();
  if (t < 64) {
    float v = s[t] + s[t + 64];
    atomicAdd(out + t, v * (1.0f / (float)n));
  }
}

extern "C" void kernel_launch(void* const* d_in, const int* in_sizes, int n_in,
                              void* d_out, int out_size, void* d_ws, size_t ws_size,
                              hipStream_t stream) {
  const float* pose = (const float*)d_in[0];
  const float* w_pos = (const float*)d_in[1];
  const float* b_pos = (const float*)d_in[2];
  const float* w_fc  = (const float*)d_in[3];
  const float* b_fc  = (const float*)d_in[4];
  const float* w_g1  = (const float*)d_in[5];
  const float* b_g1  = (const float*)d_in[6];
  const float* w_g2  = (const float*)d_in[7];
  const float* b_g2  = (const float*)d_in[8];
  const float* w_g3  = (const float*)d_in[9];
  const float* b_g3  = (const float*)d_in[10];
  const int*   edges = (const int*)d_in[11];

  const int n = in_sizes[0] / 64;   // N_NODES
  const int E = in_sizes[11] / 2;   // N_EDGES
  const int* rows = edges;
  const int* cols = edges + E;

  // workspace layout
  char* p = (char*)d_ws;
  auto alloc = [&](size_t bytes) { char* q = p; p += (bytes + 255) & ~(size_t)255; return q; };
  int*   cnt    = (int*)  alloc((size_t)n * 4);
  int*   off    = (int*)  alloc((size_t)n * 4);
  int*   cursor = (int*)  alloc((size_t)n * 4);
  int*   bsums  = (int*)  alloc(1024 * 4);
  float* dis    = (float*)alloc((size_t)n * 4);
  int*   csr    = (int*)  alloc((size_t)E * 4);
  float* bufA   = (float*)alloc((size_t)n * 128 * 4);
  float* bufB   = (float*)alloc((size_t)n * 128 * 4);

  const int e_blocks   = (E + 255) / 256;
  const int n_blocks   = (n + 255) / 256;
  const int s1_blocks  = (n + 1023) / 1024;   // 98 for n=100k (must be <=256)
  const int gemm_blocks = (n + 63) / 64;
  const int g128_blocks = (n + 1) / 2;
  const int gm_blocks   = (n + 31) / 32;

  // ---- CSR build (once; shared by all three convs) ----
  hipMemsetAsync(cnt, 0, (size_t)n * 4, stream);
  hipMemsetAsync(cursor, 0, (size_t)n * 4, stream);
  cnt_accum<<<e_blocks, 256, 0, stream>>>(cols, cnt, E);
  scan1<<<s1_blocks, 256, 0, stream>>>(cnt, off, bsums, dis, n);
  scan2<<<1, 256, 0, stream>>>(bsums, s1_blocks);
  scan3<<<n_blocks, 256, 0, stream>>>(off, bsums, n);
  fill_csr<<<e_blocks, 256, 0, stream>>>(rows, cols, off, cursor, csr, E);

  // ---- refine: x1 = lrelu(pose @ w_pos + b_pos); x2 = x1 @ w_fc + b_fc ----
  gemm_kernel<64, 128, true, false, true><<<gemm_blocks, 256, 0, stream>>>(
      pose, w_pos, b_pos, nullptr, bufA, n);
  gemm_kernel<128, 128, false, false, true><<<gemm_blocks, 256, 0, stream>>>(
      bufA, w_fc, b_fc, nullptr, bufB, n);

  // ---- conv1 ----
  gemm_kernel<128, 128, false, true, false><<<gemm_blocks, 256, 0, stream>>>(
      bufB, w_g1, nullptr, dis, bufA, n);
  gather_kernel<128><<<g128_blocks, 256, 0, stream>>>(csr, off, cnt, bufA, dis, b_g1, bufB, n);

  // ---- conv2 ----
  gemm_kernel<128, 128, false, true, false><<<gemm_blocks, 256, 0, stream>>>(
      bufB, w_g2, nullptr, dis, bufA, n);
  gather_kernel<128><<<g128_blocks, 256, 0, stream>>>(csr, off, cnt, bufA, dis, b_g2, bufB, n);

  // ---- conv3 + mean ----
  gemm_kernel<128, 64, false, true, false><<<gemm_blocks, 256, 0, stream>>>(
      bufB, w_g3, nullptr, dis, bufA, n);
  hipMemsetAsync(d_out, 0, 64 * 4, stream);
  gather_mean64<<<gm_blocks, 256, 0, stream>>>(csr, off, cnt, bufA, dis, b_g3, (float*)d_out, n);
}

// Round 3
// 803.955 us; speedup vs baseline: 8.9690x; 1.1658x over previous
//
#include <hip/hip_runtime.h>

#define SLOPE 0.01f

__device__ __forceinline__ float lrelu(float v) { return v >= 0.0f ? v : SLOPE * v; }

// ---------------- CSR build ----------------
__global__ __launch_bounds__(256) void cnt_accum(const int* __restrict__ cols,
                                                 int* __restrict__ cnt, int E) {
  int t = blockIdx.x * 256 + threadIdx.x;
  if (t < E) atomicAdd(&cnt[cols[t]], 1);
}

// per-block (1024 elems) exclusive scan; also dis = rsqrt(cnt+1)
__global__ __launch_bounds__(256) void scan1(const int* __restrict__ cnt,
                                             int* __restrict__ off,
                                             int* __restrict__ bsums,
                                             float* __restrict__ dis, int n) {
  __shared__ int s[256];
  const int t = threadIdx.x;
  const int base = blockIdx.x * 1024 + t * 4;
  int c[4];
  #pragma unroll
  for (int j = 0; j < 4; ++j) { int i = base + j; c[j] = (i < n) ? cnt[i] : 0; }
  int tsum = c[0] + c[1] + c[2] + c[3];
  s[t] = tsum;
  __syncthreads();
  for (int d = 1; d < 256; d <<= 1) {
    int v = (t >= d) ? s[t - d] : 0;
    __syncthreads();
    s[t] += v;
    __syncthreads();
  }
  int run = s[t] - tsum;
  #pragma unroll
  for (int j = 0; j < 4; ++j) {
    int i = base + j;
    if (i < n) { off[i] = run; dis[i] = rsqrtf((float)c[j] + 1.0f); }
    run += c[j];
  }
  if (t == 255) bsums[blockIdx.x] = s[255];
}

__global__ __launch_bounds__(256) void scan2(int* __restrict__ bsums, int nb) {
  __shared__ int s[256];
  const int t = threadIdx.x;
  int v = (t < nb) ? bsums[t] : 0;
  s[t] = v;
  __syncthreads();
  for (int d = 1; d < 256; d <<= 1) {
    int u = (t >= d) ? s[t - d] : 0;
    __syncthreads();
    s[t] += u;
    __syncthreads();
  }
  if (t < nb) bsums[t] = s[t] - v;
}

__global__ __launch_bounds__(256) void scan3(int* __restrict__ off,
                                             const int* __restrict__ bsums, int n) {
  int i = blockIdx.x * 256 + threadIdx.x;
  if (i < n) off[i] += bsums[i >> 10];
}

__global__ __launch_bounds__(256) void fill_csr(const int* __restrict__ rows,
                                                const int* __restrict__ cols,
                                                const int* __restrict__ off,
                                                int* __restrict__ cursor,
                                                int* __restrict__ csr, int E) {
  int e = blockIdx.x * 256 + threadIdx.x;
  if (e >= E) return;
  int c = cols[e];
  int p = off[c] + atomicAdd(&cursor[c], 1);
  csr[p] = rows[e];
}

// ---------------- GEMM: y = f((x @ W) [+bias] [*rowscale]) ----------------
template<int K, int C, bool ACT, bool SCALE, bool BIAS>
__global__ __launch_bounds__(256) void gemm_kernel(
    const float* __restrict__ x, const float* __restrict__ W,
    const float* __restrict__ bias, const float* __restrict__ rowscale,
    float* __restrict__ y, int n)
{
  constexpr int TC  = C / 8;
  constexpr int TR  = 256 / TC;
  constexpr int RPT = 64 / TR;
  constexpr int XS  = K + 4;
  __shared__ float xs[64 * XS];
  __shared__ float ws[32 * C];
  const int t = threadIdx.x;
  const int row0 = blockIdx.x * 64;

  for (int i = t; i < 64 * (K / 4); i += 256) {
    int r  = i / (K / 4);
    int kk = (i % (K / 4)) * 4;
    int rg = row0 + r;
    float4 v = make_float4(0.f, 0.f, 0.f, 0.f);
    if (rg < n) v = *(const float4*)(x + (size_t)rg * K + kk);
    float* dst = &xs[r * XS + kk];
    dst[0] = v.x; dst[1] = v.y; dst[2] = v.z; dst[3] = v.w;
  }

  const int tc = t % TC, tr = t / TC;
  const int c0 = tc * 4, c1 = C / 2 + tc * 4;
  const int rb = tr * RPT;

  float acc[RPT][8];
  #pragma unroll
  for (int i = 0; i < RPT; ++i)
    #pragma unroll
    for (int j = 0; j < 8; ++j) acc[i][j] = 0.f;

  for (int kp = 0; kp < K; kp += 32) {
    __syncthreads();
    for (int i = t; i < 32 * C / 4; i += 256)
      ((float4*)ws)[i] = ((const float4*)(W + (size_t)kp * C))[i];
    __syncthreads();

    for (int k = 0; k < 32; k += 4) {
      float xv[RPT][4];
      #pragma unroll
      for (int i = 0; i < RPT; ++i) {
        float4 tmp = *(const float4*)&xs[(rb + i) * XS + kp + k];
        xv[i][0] = tmp.x; xv[i][1] = tmp.y; xv[i][2] = tmp.z; xv[i][3] = tmp.w;
      }
      #pragma unroll
      for (int kk = 0; kk < 4; ++kk) {
        float4 w0 = *(const float4*)&ws[(k + kk) * C + c0];
        float4 w1 = *(const float4*)&ws[(k + kk) * C + c1];
        float wv[8] = {w0.x, w0.y, w0.z, w0.w, w1.x, w1.y, w1.z, w1.w};
        #pragma unroll
        for (int i = 0; i < RPT; ++i) {
          float xk = xv[i][kk];
          #pragma unroll
          for (int j = 0; j < 8; ++j) acc[i][j] = fmaf(xk, wv[j], acc[i][j]);
        }
      }
    }
  }

  float b[8];
  if (BIAS) {
    float4 b0 = *(const float4*)(bias + c0);
    float4 b1 = *(const float4*)(bias + c1);
    b[0] = b0.x; b[1] = b0.y; b[2] = b0.z; b[3] = b0.w;
    b[4] = b1.x; b[5] = b1.y; b[6] = b1.z; b[7] = b1.w;
  }
  #pragma unroll
  for (int i = 0; i < RPT; ++i) {
    int rg = row0 + rb + i;
    if (rg >= n) continue;
    float sc = SCALE ? rowscale[rg] : 1.0f;
    float o[8];
    #pragma unroll
    for (int j = 0; j < 8; ++j) {
      float v = acc[i][j];
      if (BIAS) v += b[j];
      if (SCALE) v *= sc;
      if (ACT) v = lrelu(v);
      o[j] = v;
    }
    *(float4*)(y + (size_t)rg * C + c0) = make_float4(o[0], o[1], o[2], o[3]);
    *(float4*)(y + (size_t)rg * C + c1) = make_float4(o[4], o[5], o[6], o[7]);
  }
}

// ---------------- fused gather (float4 + shfl-broadcast csr) ----------------
// GPN = C/4 threads per node; each thread owns one float4 chunk.
template<int C>
__global__ __launch_bounds__(256) void gather4_kernel(
    const int* __restrict__ csr, const int* __restrict__ off, const int* __restrict__ cnt,
    const float* __restrict__ hs, const float* __restrict__ dis,
    const float* __restrict__ bias, float* __restrict__ y, int n)
{
  constexpr int GPN = C / 4;
  constexpr int NPB = 256 / GPN;
  const int t = threadIdx.x;
  const int l = t % GPN;              // chunk index within node
  const int node = blockIdx.x * NPB + t / GPN;
  if (node >= n) return;
  const int o = off[node], d = cnt[node];

  float4 acc = make_float4(0.f, 0.f, 0.f, 0.f);
  for (int base = 0; base < d; base += GPN) {
    const int batch = min(d - base, GPN);
    int idx = (l < batch) ? csr[o + base + l] : 0;
    int j = 0;
    for (; j + 4 <= batch; j += 4) {
      int r0 = __shfl(idx, j + 0, GPN);
      int r1 = __shfl(idx, j + 1, GPN);
      int r2 = __shfl(idx, j + 2, GPN);
      int r3 = __shfl(idx, j + 3, GPN);
      float4 a0 = *(const float4*)(hs + (size_t)r0 * C + l * 4);
      float4 a1 = *(const float4*)(hs + (size_t)r1 * C + l * 4);
      float4 a2 = *(const float4*)(hs + (size_t)r2 * C + l * 4);
      float4 a3 = *(const float4*)(hs + (size_t)r3 * C + l * 4);
      float4 s01, s23;
      s01.x = a0.x + a1.x; s01.y = a0.y + a1.y; s01.z = a0.z + a1.z; s01.w = a0.w + a1.w;
      s23.x = a2.x + a3.x; s23.y = a2.y + a3.y; s23.z = a2.z + a3.z; s23.w = a2.w + a3.w;
      acc.x += s01.x + s23.x; acc.y += s01.y + s23.y;
      acc.z += s01.z + s23.z; acc.w += s01.w + s23.w;
    }
    for (; j < batch; ++j) {
      int r = __shfl(idx, j, GPN);
      float4 a = *(const float4*)(hs + (size_t)r * C + l * 4);
      acc.x += a.x; acc.y += a.y; acc.z += a.z; acc.w += a.w;
    }
  }

  const float dd = dis[node];
  float4 h  = *(const float4*)(hs + (size_t)node * C + l * 4);
  float4 b4 = *(const float4*)(bias + l * 4);
  float4 out;
  out.x = lrelu((acc.x + h.x) * dd + b4.x);
  out.y = lrelu((acc.y + h.y) * dd + b4.y);
  out.z = lrelu((acc.z + h.z) * dd + b4.z);
  out.w = lrelu((acc.w + h.w) * dd + b4.w);
  *(float4*)(y + (size_t)node * C + l * 4) = out;
}

// ---------------- conv3: gather + finalize + mean (C=64, GPN=16) ----------------
template<int NPG>
__global__ __launch_bounds__(256) void gather_mean64_v2(
    const int* __restrict__ csr, const int* __restrict__ off, const int* __restrict__ cnt,
    const float* __restrict__ hs, const float* __restrict__ dis,
    const float* __restrict__ bias, float* __restrict__ out, int n)
{
  constexpr int GPN = 16;
  const int t = threadIdx.x;
  const int l = t % GPN;
  const int g = t / GPN;              // 0..15
  float4 b4 = *(const float4*)(bias + l * 4);
  float4 colsum = make_float4(0.f, 0.f, 0.f, 0.f);
  const int base_node = blockIdx.x * 16 * NPG + g * NPG;

  for (int gi = 0; gi < NPG; ++gi) {
    const int node = base_node + gi;
    if (node >= n) break;
    const int o = off[node], d = cnt[node];
    float4 acc = make_float4(0.f, 0.f, 0.f, 0.f);
    for (int base = 0; base < d; base += GPN) {
      const int batch = min(d - base, GPN);
      int idx = (l < batch) ? csr[o + base + l] : 0;
      int j = 0;
      for (; j + 4 <= batch; j += 4) {
        int r0 = __shfl(idx, j + 0, GPN);
        int r1 = __shfl(idx, j + 1, GPN);
        int r2 = __shfl(idx, j + 2, GPN);
        int r3 = __shfl(idx, j + 3, GPN);
        float4 a0 = *(const float4*)(hs + (size_t)r0 * 64 + l * 4);
        float4 a1 = *(const float4*)(hs + (size_t)r1 * 64 + l * 4);
        float4 a2 = *(const float4*)(hs + (size_t)r2 * 64 + l * 4);
        float4 a3 = *(const float4*)(hs + (size_t)r3 * 64 + l * 4);
        acc.x += (a0.x + a1.x) + (a2.x + a3.x);
        acc.y += (a0.y + a1.y) + (a2.y + a3.y);
        acc.z += (a0.z + a1.z) + (a2.z + a3.z);
        acc.w += (a0.w + a1.w) + (a2.w + a3.w);
      }
      for (; j < batch; ++j) {
        int r = __shfl(idx, j, GPN);
        float4 a = *(const float4*)(hs + (size_t)r * 64 + l * 4);
        acc.x += a.x; acc.y += a.y; acc.z += a.z; acc.w += a.w;
      }
    }
    const float dd = dis[node];
    float4 h = *(const float4*)(hs + (size_t)node * 64 + l * 4);
    colsum.x += lrelu((acc.x + h.x) * dd + b4.x);
    colsum.y += lrelu((acc.y + h.y) * dd + b4.y);
    colsum.z += lrelu((acc.z + h.z) * dd + b4.z);
    colsum.w += lrelu((acc.w + h.w) * dd + b4.w);
  }

  __shared__ float4 s[256];
  s[t] = colsum;
  __syncthreads();
  for (int offst = 128; offst >= 16; offst >>= 1) {
    if (t < offst) {
      s[t].x += s[t + offst].x; s[t].y += s[t + offst].y;
      s[t].z += s[t + offst].z; s[t].w += s[t + offst].w;
    }
    __syncthreads();
  }
  if (t < 16) {
    const float inv = 1.0f / (float)n;
    atomicAdd(out + t * 4 + 0, s[t].x * inv);
    atomicAdd(out + t * 4 + 1, s[t].y * inv);
    atomicAdd(out + t * 4 + 2, s[t].z * inv);
    atomicAdd(out + t * 4 + 3, s[t].w * inv);
  }
}

extern "C" void kernel_launch(void* const* d_in, const int* in_sizes, int n_in,
                              void* d_out, int out_size, void* d_ws, size_t ws_size,
                              hipStream_t stream) {
  const float* pose = (const float*)d_in[0];
  const float* w_pos = (const float*)d_in[1];
  const float* b_pos = (const float*)d_in[2];
  const float* w_fc  = (const float*)d_in[3];
  const float* b_fc  = (const float*)d_in[4];
  const float* w_g1  = (const float*)d_in[5];
  const float* b_g1  = (const float*)d_in[6];
  const float* w_g2  = (const float*)d_in[7];
  const float* b_g2  = (const float*)d_in[8];
  const float* w_g3  = (const float*)d_in[9];
  const float* b_g3  = (const float*)d_in[10];
  const int*   edges = (const int*)d_in[11];

  const int n = in_sizes[0] / 64;   // N_NODES
  const int E = in_sizes[11] / 2;   // N_EDGES
  const int* rows = edges;
  const int* cols = edges + E;

  char* p = (char*)d_ws;
  auto alloc = [&](size_t bytes) { char* q = p; p += (bytes + 255) & ~(size_t)255; return q; };
  int*   cnt    = (int*)  alloc((size_t)n * 4);
  int*   off    = (int*)  alloc((size_t)n * 4);
  int*   cursor = (int*)  alloc((size_t)n * 4);
  int*   bsums  = (int*)  alloc(1024 * 4);
  float* dis    = (float*)alloc((size_t)n * 4);
  int*   csr    = (int*)  alloc((size_t)E * 4);
  float* bufA   = (float*)alloc((size_t)n * 128 * 4);
  float* bufB   = (float*)alloc((size_t)n * 128 * 4);

  const int e_blocks    = (E + 255) / 256;
  const int n_blocks    = (n + 255) / 256;
  const int s1_blocks   = (n + 1023) / 1024;
  const int gemm_blocks = (n + 63) / 64;
  const int g4_blocks   = (n + 7) / 8;          // gather4<128>: 8 nodes/block
  constexpr int NPG = 8;
  const int gm_blocks   = (n + 16 * NPG - 1) / (16 * NPG);

  // ---- CSR build ----
  hipMemsetAsync(cnt, 0, (size_t)n * 4, stream);
  hipMemsetAsync(cursor, 0, (size_t)n * 4, stream);
  cnt_accum<<<e_blocks, 256, 0, stream>>>(cols, cnt, E);
  scan1<<<s1_blocks, 256, 0, stream>>>(cnt, off, bsums, dis, n);
  scan2<<<1, 256, 0, stream>>>(bsums, s1_blocks);
  scan3<<<n_blocks, 256, 0, stream>>>(off, bsums, n);
  fill_csr<<<e_blocks, 256, 0, stream>>>(rows, cols, off, cursor, csr, E);

  // ---- refine ----
  gemm_kernel<64, 128, true, false, true><<<gemm_blocks, 256, 0, stream>>>(
      pose, w_pos, b_pos, nullptr, bufA, n);
  gemm_kernel<128, 128, false, false, true><<<gemm_blocks, 256, 0, stream>>>(
      bufA, w_fc, b_fc, nullptr, bufB, n);

  // ---- conv1 ----
  gemm_kernel<128, 128, false, true, false><<<gemm_blocks, 256, 0, stream>>>(
      bufB, w_g1, nullptr, dis, bufA, n);
  gather4_kernel<128><<<g4_blocks, 256, 0, stream>>>(csr, off, cnt, bufA, dis, b_g1, bufB, n);

  // ---- conv2 ----
  gemm_kernel<128, 128, false, true, false><<<gemm_blocks, 256, 0, stream>>>(
      bufB, w_g2, nullptr, dis, bufA, n);
  gather4_kernel<128><<<g4_blocks, 256, 0, stream>>>(csr, off, cnt, bufA, dis, b_g2, bufB, n);

  // ---- conv3 + mean ----
  gemm_kernel<128, 64, false, true, false><<<gemm_blocks, 256, 0, stream>>>(
      bufB, w_g3, nullptr, dis, bufA, n);
  hipMemsetAsync(d_out, 0, 64 * 4, stream);
  gather_mean64_v2<NPG><<<gm_blocks, 256, 0, stream>>>(csr, off, cnt, bufA, dis, b_g3, (float*)d_out, n);
}

// Round 4
// 735.258 us; speedup vs baseline: 9.8070x; 1.0934x over previous
//
#include <hip/hip_runtime.h>

#define SLOPE 0.01f

__device__ __forceinline__ float lrelu(float v) { return v >= 0.0f ? v : SLOPE * v; }

// ---------------- CSR build ----------------
__global__ __launch_bounds__(256) void cnt_accum(const int* __restrict__ cols,
                                                 int* __restrict__ cnt, int E) {
  int t = blockIdx.x * 256 + threadIdx.x;
  if (t < E) atomicAdd(&cnt[cols[t]], 1);
}

// per-block (1024 elems) exclusive scan; also dis = rsqrt(cnt+1)
__global__ __launch_bounds__(256) void scan1(const int* __restrict__ cnt,
                                             int* __restrict__ off,
                                             int* __restrict__ bsums,
                                             float* __restrict__ dis, int n) {
  __shared__ int s[256];
  const int t = threadIdx.x;
  const int base = blockIdx.x * 1024 + t * 4;
  int c[4];
  #pragma unroll
  for (int j = 0; j < 4; ++j) { int i = base + j; c[j] = (i < n) ? cnt[i] : 0; }
  int tsum = c[0] + c[1] + c[2] + c[3];
  s[t] = tsum;
  __syncthreads();
  for (int d = 1; d < 256; d <<= 1) {
    int v = (t >= d) ? s[t - d] : 0;
    __syncthreads();
    s[t] += v;
    __syncthreads();
  }
  int run = s[t] - tsum;
  #pragma unroll
  for (int j = 0; j < 4; ++j) {
    int i = base + j;
    if (i < n) { off[i] = run; dis[i] = rsqrtf((float)c[j] + 1.0f); }
    run += c[j];
  }
  if (t == 255) bsums[blockIdx.x] = s[255];
}

__global__ __launch_bounds__(256) void scan2(int* __restrict__ bsums, int nb) {
  __shared__ int s[256];
  const int t = threadIdx.x;
  int v = (t < nb) ? bsums[t] : 0;
  s[t] = v;
  __syncthreads();
  for (int d = 1; d < 256; d <<= 1) {
    int u = (t >= d) ? s[t - d] : 0;
    __syncthreads();
    s[t] += u;
    __syncthreads();
  }
  if (t < nb) bsums[t] = s[t] - v;
}

__global__ __launch_bounds__(256) void scan3(int* __restrict__ off,
                                             const int* __restrict__ bsums, int n, int E) {
  int i = blockIdx.x * 256 + threadIdx.x;
  if (i < n) off[i] += bsums[i >> 10];
  if (i == 0) off[n] = E;
}

// fill using cnt as reverse cursor (destroys cnt; degree recovered from off diff)
__global__ __launch_bounds__(256) void fill_csr(const int* __restrict__ rows,
                                                const int* __restrict__ cols,
                                                const int* __restrict__ off,
                                                int* __restrict__ cnt,
                                                int* __restrict__ csr, int E) {
  int e = blockIdx.x * 256 + threadIdx.x;
  if (e >= E) return;
  int c = cols[e];
  int p = off[c] + atomicAdd(&cnt[c], -1) - 1;
  csr[p] = rows[e];
}

// ---------------- GEMM: y = f((x @ W) [+bias] [*rowscale]) ----------------
template<int K, int C, bool ACT, bool SCALE, bool BIAS>
__global__ __launch_bounds__(256) void gemm_kernel(
    const float* __restrict__ x, const float* __restrict__ W,
    const float* __restrict__ bias, const float* __restrict__ rowscale,
    float* __restrict__ y, int n)
{
  constexpr int TC  = C / 8;
  constexpr int TR  = 256 / TC;
  constexpr int RPT = 64 / TR;
  constexpr int XS  = K + 4;
  __shared__ float xs[64 * XS];
  __shared__ float ws[32 * C];
  const int t = threadIdx.x;
  const int row0 = blockIdx.x * 64;

  for (int i = t; i < 64 * (K / 4); i += 256) {
    int r  = i / (K / 4);
    int kk = (i % (K / 4)) * 4;
    int rg = row0 + r;
    float4 v = make_float4(0.f, 0.f, 0.f, 0.f);
    if (rg < n) v = *(const float4*)(x + (size_t)rg * K + kk);
    float* dst = &xs[r * XS + kk];
    dst[0] = v.x; dst[1] = v.y; dst[2] = v.z; dst[3] = v.w;
  }

  const int tc = t % TC, tr = t / TC;
  const int c0 = tc * 4, c1 = C / 2 + tc * 4;
  const int rb = tr * RPT;

  float acc[RPT][8];
  #pragma unroll
  for (int i = 0; i < RPT; ++i)
    #pragma unroll
    for (int j = 0; j < 8; ++j) acc[i][j] = 0.f;

  for (int kp = 0; kp < K; kp += 32) {
    __syncthreads();
    for (int i = t; i < 32 * C / 4; i += 256)
      ((float4*)ws)[i] = ((const float4*)(W + (size_t)kp * C))[i];
    __syncthreads();

    for (int k = 0; k < 32; k += 4) {
      float xv[RPT][4];
      #pragma unroll
      for (int i = 0; i < RPT; ++i) {
        float4 tmp = *(const float4*)&xs[(rb + i) * XS + kp + k];
        xv[i][0] = tmp.x; xv[i][1] = tmp.y; xv[i][2] = tmp.z; xv[i][3] = tmp.w;
      }
      #pragma unroll
      for (int kk = 0; kk < 4; ++kk) {
        float4 w0 = *(const float4*)&ws[(k + kk) * C + c0];
        float4 w1 = *(const float4*)&ws[(k + kk) * C + c1];
        float wv[8] = {w0.x, w0.y, w0.z, w0.w, w1.x, w1.y, w1.z, w1.w};
        #pragma unroll
        for (int i = 0; i < RPT; ++i) {
          float xk = xv[i][kk];
          #pragma unroll
          for (int j = 0; j < 8; ++j) acc[i][j] = fmaf(xk, wv[j], acc[i][j]);
        }
      }
    }
  }

  float b[8];
  if (BIAS) {
    float4 b0 = *(const float4*)(bias + c0);
    float4 b1 = *(const float4*)(bias + c1);
    b[0] = b0.x; b[1] = b0.y; b[2] = b0.z; b[3] = b0.w;
    b[4] = b1.x; b[5] = b1.y; b[6] = b1.z; b[7] = b1.w;
  }
  #pragma unroll
  for (int i = 0; i < RPT; ++i) {
    int rg = row0 + rb + i;
    if (rg >= n) continue;
    float sc = SCALE ? rowscale[rg] : 1.0f;
    float o[8];
    #pragma unroll
    for (int j = 0; j < 8; ++j) {
      float v = acc[i][j];
      if (BIAS) v += b[j];
      if (SCALE) v *= sc;
      if (ACT) v = lrelu(v);
      o[j] = v;
    }
    *(float4*)(y + (size_t)rg * C + c0) = make_float4(o[0], o[1], o[2], o[3]);
    *(float4*)(y + (size_t)rg * C + c1) = make_float4(o[4], o[5], o[6], o[7]);
  }
}

// ---------------- fused gather (float4 + shfl-broadcast csr, unroll 8) ----------------
template<int C>
__global__ __launch_bounds__(256) void gather4_kernel(
    const int* __restrict__ csr, const int* __restrict__ off,
    const float* __restrict__ hs, const float* __restrict__ dis,
    const float* __restrict__ bias, float* __restrict__ y, int n)
{
  constexpr int GPN = C / 4;
  constexpr int NPB = 256 / GPN;
  const int t = threadIdx.x;
  const int l = t % GPN;
  const int node = blockIdx.x * NPB + t / GPN;
  if (node >= n) return;
  const int o = off[node];
  const int d = off[node + 1] - o;

  float4 acc = make_float4(0.f, 0.f, 0.f, 0.f);
  for (int base = 0; base < d; base += GPN) {
    const int batch = min(d - base, GPN);
    int idx = (l < batch) ? csr[o + base + l] : 0;
    int j = 0;
    for (; j + 8 <= batch; j += 8) {
      float4 a[8];
      #pragma unroll
      for (int u = 0; u < 8; ++u) {
        int r = __shfl(idx, j + u, GPN);
        a[u] = *(const float4*)(hs + (size_t)r * C + l * 4);
      }
      #pragma unroll
      for (int u = 0; u < 8; u += 2) {
        acc.x += a[u].x + a[u + 1].x; acc.y += a[u].y + a[u + 1].y;
        acc.z += a[u].z + a[u + 1].z; acc.w += a[u].w + a[u + 1].w;
      }
    }
    for (; j < batch; ++j) {
      int r = __shfl(idx, j, GPN);
      float4 a = *(const float4*)(hs + (size_t)r * C + l * 4);
      acc.x += a.x; acc.y += a.y; acc.z += a.z; acc.w += a.w;
    }
  }

  const float dd = dis[node];
  float4 h  = *(const float4*)(hs + (size_t)node * C + l * 4);
  float4 b4 = *(const float4*)(bias + l * 4);
  float4 out;
  out.x = lrelu((acc.x + h.x) * dd + b4.x);
  out.y = lrelu((acc.y + h.y) * dd + b4.y);
  out.z = lrelu((acc.z + h.z) * dd + b4.z);
  out.w = lrelu((acc.w + h.w) * dd + b4.w);
  *(float4*)(y + (size_t)node * C + l * 4) = out;
}

// ---------------- conv3: gather + finalize + block partial sums (C=64) ----------------
// 16 lanes per node, 16 nodes per block; partial colsum -> 32 replicated slots.
__global__ __launch_bounds__(256) void gather_mean_part(
    const int* __restrict__ csr, const int* __restrict__ off,
    const float* __restrict__ hs, const float* __restrict__ dis,
    const float* __restrict__ bias, float* __restrict__ partial, int n)
{
  constexpr int GPN = 16;
  const int t = threadIdx.x;
  const int l = t % GPN;
  const int node = blockIdx.x * 16 + t / GPN;
  float4 b4 = *(const float4*)(bias + l * 4);
  float4 val = make_float4(0.f, 0.f, 0.f, 0.f);

  if (node < n) {
    const int o = off[node];
    const int d = off[node + 1] - o;
    float4 acc = make_float4(0.f, 0.f, 0.f, 0.f);
    for (int base = 0; base < d; base += GPN) {
      const int batch = min(d - base, GPN);
      int idx = (l < batch) ? csr[o + base + l] : 0;
      int j = 0;
      for (; j + 8 <= batch; j += 8) {
        float4 a[8];
        #pragma unroll
        for (int u = 0; u < 8; ++u) {
          int r = __shfl(idx, j + u, GPN);
          a[u] = *(const float4*)(hs + (size_t)r * 64 + l * 4);
        }
        #pragma unroll
        for (int u = 0; u < 8; u += 2) {
          acc.x += a[u].x + a[u + 1].x; acc.y += a[u].y + a[u + 1].y;
          acc.z += a[u].z + a[u + 1].z; acc.w += a[u].w + a[u + 1].w;
        }
      }
      for (; j < batch; ++j) {
        int r = __shfl(idx, j, GPN);
        float4 a = *(const float4*)(hs + (size_t)r * 64 + l * 4);
        acc.x += a.x; acc.y += a.y; acc.z += a.z; acc.w += a.w;
      }
    }
    const float dd = dis[node];
    float4 h = *(const float4*)(hs + (size_t)node * 64 + l * 4);
    val.x = lrelu((acc.x + h.x) * dd + b4.x);
    val.y = lrelu((acc.y + h.y) * dd + b4.y);
    val.z = lrelu((acc.z + h.z) * dd + b4.z);
    val.w = lrelu((acc.w + h.w) * dd + b4.w);
  }

  __shared__ float4 s[256];
  s[t] = val;
  __syncthreads();
  // sum across the 16 node-groups for each lane l (stride-16 classes)
  for (int offst = 128; offst >= 16; offst >>= 1) {
    if (t < offst) {
      s[t].x += s[t + offst].x; s[t].y += s[t + offst].y;
      s[t].z += s[t + offst].z; s[t].w += s[t + offst].w;
    }
    __syncthreads();
  }
  if (t < 16) {
    float* slot = partial + (size_t)(blockIdx.x & 31) * 64;
    atomicAdd(slot + t * 4 + 0, s[t].x);
    atomicAdd(slot + t * 4 + 1, s[t].y);
    atomicAdd(slot + t * 4 + 2, s[t].z);
    atomicAdd(slot + t * 4 + 3, s[t].w);
  }
}

__global__ __launch_bounds__(64) void mean_finish(const float* __restrict__ partial,
                                                  float* __restrict__ out, int n) {
  const int c = threadIdx.x;  // 0..63
  float s = 0.f;
  #pragma unroll
  for (int k = 0; k < 32; ++k) s += partial[k * 64 + c];
  out[c] = s / (float)n;
}

extern "C" void kernel_launch(void* const* d_in, const int* in_sizes, int n_in,
                              void* d_out, int out_size, void* d_ws, size_t ws_size,
                              hipStream_t stream) {
  const float* pose = (const float*)d_in[0];
  const float* w_pos = (const float*)d_in[1];
  const float* b_pos = (const float*)d_in[2];
  const float* w_fc  = (const float*)d_in[3];
  const float* b_fc  = (const float*)d_in[4];
  const float* w_g1  = (const float*)d_in[5];
  const float* b_g1  = (const float*)d_in[6];
  const float* w_g2  = (const float*)d_in[7];
  const float* b_g2  = (const float*)d_in[8];
  const float* w_g3  = (const float*)d_in[9];
  const float* b_g3  = (const float*)d_in[10];
  const int*   edges = (const int*)d_in[11];

  const int n = in_sizes[0] / 64;   // N_NODES
  const int E = in_sizes[11] / 2;   // N_EDGES
  const int* rows = edges;
  const int* cols = edges + E;

  char* p = (char*)d_ws;
  auto alloc = [&](size_t bytes) { char* q = p; p += (bytes + 255) & ~(size_t)255; return q; };
  int*   cnt     = (int*)  alloc((size_t)n * 4);
  int*   off     = (int*)  alloc((size_t)(n + 1) * 4);
  int*   bsums   = (int*)  alloc(1024 * 4);
  float* dis     = (float*)alloc((size_t)n * 4);
  float* partial = (float*)alloc(32 * 64 * 4);
  int*   csr     = (int*)  alloc((size_t)E * 4);
  float* bufA    = (float*)alloc((size_t)n * 128 * 4);
  float* bufB    = (float*)alloc((size_t)n * 128 * 4);

  const int e_blocks    = (E + 255) / 256;
  const int n_blocks    = (n + 255) / 256;
  const int s1_blocks   = (n + 1023) / 1024;
  const int gemm_blocks = (n + 63) / 64;
  const int g4_blocks   = (n + 7) / 8;       // gather4<128>: 8 nodes/block
  const int gm_blocks   = (n + 15) / 16;     // gather_mean_part: 16 nodes/block

  // ---- CSR build ----
  hipMemsetAsync(cnt, 0, (size_t)n * 4, stream);
  hipMemsetAsync(partial, 0, 32 * 64 * 4, stream);
  cnt_accum<<<e_blocks, 256, 0, stream>>>(cols, cnt, E);
  scan1<<<s1_blocks, 256, 0, stream>>>(cnt, off, bsums, dis, n);
  scan2<<<1, 256, 0, stream>>>(bsums, s1_blocks);
  scan3<<<n_blocks, 256, 0, stream>>>(off, bsums, n, E);
  fill_csr<<<e_blocks, 256, 0, stream>>>(rows, cols, off, cnt, csr, E);

  // ---- refine ----
  gemm_kernel<64, 128, true, false, true><<<gemm_blocks, 256, 0, stream>>>(
      pose, w_pos, b_pos, nullptr, bufA, n);
  gemm_kernel<128, 128, false, false, true><<<gemm_blocks, 256, 0, stream>>>(
      bufA, w_fc, b_fc, nullptr, bufB, n);

  // ---- conv1 ----
  gemm_kernel<128, 128, false, true, false><<<gemm_blocks, 256, 0, stream>>>(
      bufB, w_g1, nullptr, dis, bufA, n);
  gather4_kernel<128><<<g4_blocks, 256, 0, stream>>>(csr, off, bufA, dis, b_g1, bufB, n);

  // ---- conv2 ----
  gemm_kernel<128, 128, false, true, false><<<gemm_blocks, 256, 0, stream>>>(
      bufB, w_g2, nullptr, dis, bufA, n);
  gather4_kernel<128><<<g4_blocks, 256, 0, stream>>>(csr, off, bufA, dis, b_g2, bufB, n);

  // ---- conv3 + mean ----
  gemm_kernel<128, 64, false, true, false><<<gemm_blocks, 256, 0, stream>>>(
      bufB, w_g3, nullptr, dis, bufA, n);
  gather_mean_part<<<gm_blocks, 256, 0, stream>>>(csr, off, bufA, dis, b_g3, partial, n);
  mean_finish<<<1, 64, 0, stream>>>(partial, (float*)d_out, n);
}

// Round 5
// 621.383 us; speedup vs baseline: 11.6042x; 1.1833x over previous
//
#include <hip/hip_runtime.h>

#define SLOPE 0.01f

typedef __attribute__((ext_vector_type(8))) short short8;
typedef __attribute__((ext_vector_type(4))) float f32x4;

__device__ __forceinline__ float lrelu(float v) { return v >= 0.0f ? v : SLOPE * v; }

__device__ __forceinline__ unsigned short f2bf(float f) {
  unsigned int u = __float_as_uint(f);
  return (unsigned short)((u + 0x7FFF + ((u >> 16) & 1)) >> 16);
}
__device__ __forceinline__ float bf2f(unsigned short h) {
  return __uint_as_float(((unsigned int)h) << 16);
}

// ---------------- CSR build ----------------
__global__ __launch_bounds__(256) void cnt_accum(const int* __restrict__ cols,
                                                 int* __restrict__ cnt, int E) {
  int t = blockIdx.x * 256 + threadIdx.x;
  if (t < E) atomicAdd(&cnt[cols[t]], 1);
}

__global__ __launch_bounds__(256) void scan1(const int* __restrict__ cnt,
                                             int* __restrict__ off,
                                             int* __restrict__ bsums,
                                             float* __restrict__ dis, int n) {
  __shared__ int s[256];
  const int t = threadIdx.x;
  const int base = blockIdx.x * 1024 + t * 4;
  int c[4];
  #pragma unroll
  for (int j = 0; j < 4; ++j) { int i = base + j; c[j] = (i < n) ? cnt[i] : 0; }
  int tsum = c[0] + c[1] + c[2] + c[3];
  s[t] = tsum;
  __syncthreads();
  for (int d = 1; d < 256; d <<= 1) {
    int v = (t >= d) ? s[t - d] : 0;
    __syncthreads();
    s[t] += v;
    __syncthreads();
  }
  int run = s[t] - tsum;
  #pragma unroll
  for (int j = 0; j < 4; ++j) {
    int i = base + j;
    if (i < n) { off[i] = run; dis[i] = rsqrtf((float)c[j] + 1.0f); }
    run += c[j];
  }
  if (t == 255) bsums[blockIdx.x] = s[255];
}

__global__ __launch_bounds__(256) void scan2(int* __restrict__ bsums, int nb) {
  __shared__ int s[256];
  const int t = threadIdx.x;
  int v = (t < nb) ? bsums[t] : 0;
  s[t] = v;
  __syncthreads();
  for (int d = 1; d < 256; d <<= 1) {
    int u = (t >= d) ? s[t - d] : 0;
    __syncthreads();
    s[t] += u;
    __syncthreads();
  }
  if (t < nb) bsums[t] = s[t] - v;
}

__global__ __launch_bounds__(256) void scan3(int* __restrict__ off,
                                             const int* __restrict__ bsums, int n, int E) {
  int i = blockIdx.x * 256 + threadIdx.x;
  if (i < n) off[i] += bsums[i >> 10];
  if (i == 0) off[n] = E;
}

__global__ __launch_bounds__(256) void fill_csr(const int* __restrict__ rows,
                                                const int* __restrict__ cols,
                                                const int* __restrict__ off,
                                                int* __restrict__ cnt,
                                                int* __restrict__ csr, int E) {
  int e = blockIdx.x * 256 + threadIdx.x;
  if (e >= E) return;
  int c = cols[e];
  int p = off[c] + atomicAdd(&cnt[c], -1) - 1;
  csr[p] = rows[e];
}

// ---------------- W pack: fragment-ordered bf16 hi/lo ----------------
// frag index f = (ct*KS + ks)*64 + lane ; elem b: W[ks*32+(lane>>4)*8+b][ct*16+(lane&15)]
__global__ __launch_bounds__(256) void pack_w(const float* __restrict__ W,
                                              unsigned short* __restrict__ hi,
                                              unsigned short* __restrict__ lo,
                                              int K, int C) {
  const int KS = K / 32, CT = C / 16;
  int t = blockIdx.x * 256 + threadIdx.x;
  int total = CT * KS * 64;
  if (t >= total) return;
  int l = t & 63;
  int rest = t >> 6;
  int ks = rest % KS;
  int ct = rest / KS;
  int k0 = ks * 32 + (l >> 4) * 8;
  int c  = ct * 16 + (l & 15);
  unsigned short h8[8], l8[8];
  #pragma unroll
  for (int b = 0; b < 8; ++b) {
    float v = W[(size_t)(k0 + b) * C + c];
    unsigned short h = f2bf(v);
    h8[b] = h;
    l8[b] = f2bf(v - bf2f(h));
  }
  short8 hv, lv;
  #pragma unroll
  for (int b = 0; b < 8; ++b) { hv[b] = (short)h8[b]; lv[b] = (short)l8[b]; }
  ((short8*)hi)[t] = hv;
  ((short8*)lo)[t] = lv;
}

// ---------------- MFMA GEMM (bf16x3): y = f((x @ W) [+bias] [*rowscale]) ----------------
// block = 256 = 4 waves; each wave: 16 rows x C cols. x read as f32, split hi/lo in-register.
template<int K, int C, bool ACT, bool SCALE, bool BIAS>
__global__ __launch_bounds__(256) void gemm_mfma(
    const float* __restrict__ x,
    const unsigned short* __restrict__ whi, const unsigned short* __restrict__ wlo,
    const float* __restrict__ bias, const float* __restrict__ rowscale,
    float* __restrict__ y, int n)
{
  constexpr int NC = C / 16;
  constexpr int KS = K / 32;
  const int t = threadIdx.x;
  const int w = t >> 6;
  const int lane = t & 63;
  const int row_base = blockIdx.x * 64 + w * 16;
  const int arow_raw = row_base + (lane & 15);
  const int arow = (arow_raw < n) ? arow_raw : 0;
  const int asub = (lane >> 4) * 8;
  const float* xrow = x + (size_t)arow * K + asub;

  f32x4 acc[NC];
  #pragma unroll
  for (int ct = 0; ct < NC; ++ct) acc[ct] = (f32x4){0.f, 0.f, 0.f, 0.f};

  const short8* WH = (const short8*)whi;
  const short8* WL = (const short8*)wlo;

  #pragma unroll
  for (int ks = 0; ks < KS; ++ks) {
    float4 v0 = *(const float4*)(xrow + ks * 32);
    float4 v1 = *(const float4*)(xrow + ks * 32 + 4);
    float xv[8] = {v0.x, v0.y, v0.z, v0.w, v1.x, v1.y, v1.z, v1.w};
    short8 ah, al;
    #pragma unroll
    for (int b = 0; b < 8; ++b) {
      unsigned short h = f2bf(xv[b]);
      ah[b] = (short)h;
      al[b] = (short)f2bf(xv[b] - bf2f(h));
    }
    #pragma unroll
    for (int ct = 0; ct < NC; ++ct) {
      short8 bh = WH[(ct * KS + ks) * 64 + lane];
      short8 bl = WL[(ct * KS + ks) * 64 + lane];
      acc[ct] = __builtin_amdgcn_mfma_f32_16x16x32_bf16(ah, bh, acc[ct], 0, 0, 0);
      acc[ct] = __builtin_amdgcn_mfma_f32_16x16x32_bf16(ah, bl, acc[ct], 0, 0, 0);
      acc[ct] = __builtin_amdgcn_mfma_f32_16x16x32_bf16(al, bh, acc[ct], 0, 0, 0);
    }
  }

  // epilogue: D[row=(lane>>4)*4+r][col=ct*16+(lane&15)]
  const int colb = lane & 15;
  const int rsub = (lane >> 4) * 4;
  float bcol[NC];
  #pragma unroll
  for (int ct = 0; ct < NC; ++ct) bcol[ct] = BIAS ? bias[ct * 16 + colb] : 0.f;

  #pragma unroll
  for (int r = 0; r < 4; ++r) {
    int row = row_base + rsub + r;
    if (row >= n) continue;
    float sc = SCALE ? rowscale[row] : 1.0f;
    #pragma unroll
    for (int ct = 0; ct < NC; ++ct) {
      float v = acc[ct][r];
      if (BIAS) v += bcol[ct];
      if (SCALE) v *= sc;
      if (ACT) v = lrelu(v);
      y[(size_t)row * C + ct * 16 + colb] = v;
    }
  }
}

// ---------------- fused gather (float4 + shfl-broadcast csr, unroll 8) ----------------
template<int C>
__global__ __launch_bounds__(256) void gather4_kernel(
    const int* __restrict__ csr, const int* __restrict__ off,
    const float* __restrict__ hs, const float* __restrict__ dis,
    const float* __restrict__ bias, float* __restrict__ y, int n)
{
  constexpr int GPN = C / 4;
  constexpr int NPB = 256 / GPN;
  const int t = threadIdx.x;
  const int l = t % GPN;
  const int node = blockIdx.x * NPB + t / GPN;
  if (node >= n) return;
  const int o = off[node];
  const int d = off[node + 1] - o;

  float4 acc = make_float4(0.f, 0.f, 0.f, 0.f);
  for (int base = 0; base < d; base += GPN) {
    const int batch = min(d - base, GPN);
    int idx = (l < batch) ? csr[o + base + l] : 0;
    int j = 0;
    for (; j + 8 <= batch; j += 8) {
      float4 a[8];
      #pragma unroll
      for (int u = 0; u < 8; ++u) {
        int r = __shfl(idx, j + u, GPN);
        a[u] = *(const float4*)(hs + (size_t)r * C + l * 4);
      }
      #pragma unroll
      for (int u = 0; u < 8; u += 2) {
        acc.x += a[u].x + a[u + 1].x; acc.y += a[u].y + a[u + 1].y;
        acc.z += a[u].z + a[u + 1].z; acc.w += a[u].w + a[u + 1].w;
      }
    }
    for (; j < batch; ++j) {
      int r = __shfl(idx, j, GPN);
      float4 a = *(const float4*)(hs + (size_t)r * C + l * 4);
      acc.x += a.x; acc.y += a.y; acc.z += a.z; acc.w += a.w;
    }
  }

  const float dd = dis[node];
  float4 h  = *(const float4*)(hs + (size_t)node * C + l * 4);
  float4 b4 = *(const float4*)(bias + l * 4);
  float4 out;
  out.x = lrelu((acc.x + h.x) * dd + b4.x);
  out.y = lrelu((acc.y + h.y) * dd + b4.y);
  out.z = lrelu((acc.z + h.z) * dd + b4.z);
  out.w = lrelu((acc.w + h.w) * dd + b4.w);
  *(float4*)(y + (size_t)node * C + l * 4) = out;
}

// ---------------- conv3: gather + finalize + block partial sums (C=64) ----------------
__global__ __launch_bounds__(256) void gather_mean_part(
    const int* __restrict__ csr, const int* __restrict__ off,
    const float* __restrict__ hs, const float* __restrict__ dis,
    const float* __restrict__ bias, float* __restrict__ partial, int n)
{
  constexpr int GPN = 16;
  const int t = threadIdx.x;
  const int l = t % GPN;
  const int node = blockIdx.x * 16 + t / GPN;
  float4 b4 = *(const float4*)(bias + l * 4);
  float4 val = make_float4(0.f, 0.f, 0.f, 0.f);

  if (node < n) {
    const int o = off[node];
    const int d = off[node + 1] - o;
    float4 acc = make_float4(0.f, 0.f, 0.f, 0.f);
    for (int base = 0; base < d; base += GPN) {
      const int batch = min(d - base, GPN);
      int idx = (l < batch) ? csr[o + base + l] : 0;
      int j = 0;
      for (; j + 8 <= batch; j += 8) {
        float4 a[8];
        #pragma unroll
        for (int u = 0; u < 8; ++u) {
          int r = __shfl(idx, j + u, GPN);
          a[u] = *(const float4*)(hs + (size_t)r * 64 + l * 4);
        }
        #pragma unroll
        for (int u = 0; u < 8; u += 2) {
          acc.x += a[u].x + a[u + 1].x; acc.y += a[u].y + a[u + 1].y;
          acc.z += a[u].z + a[u + 1].z; acc.w += a[u].w + a[u + 1].w;
        }
      }
      for (; j < batch; ++j) {
        int r = __shfl(idx, j, GPN);
        float4 a = *(const float4*)(hs + (size_t)r * 64 + l * 4);
        acc.x += a.x; acc.y += a.y; acc.z += a.z; acc.w += a.w;
      }
    }
    const float dd = dis[node];
    float4 h = *(const float4*)(hs + (size_t)node * 64 + l * 4);
    val.x = lrelu((acc.x + h.x) * dd + b4.x);
    val.y = lrelu((acc.y + h.y) * dd + b4.y);
    val.z = lrelu((acc.z + h.z) * dd + b4.z);
    val.w = lrelu((acc.w + h.w) * dd + b4.w);
  }

  __shared__ float4 s[256];
  s[t] = val;
  __syncthreads();
  for (int offst = 128; offst >= 16; offst >>= 1) {
    if (t < offst) {
      s[t].x += s[t + offst].x; s[t].y += s[t + offst].y;
      s[t].z += s[t + offst].z; s[t].w += s[t + offst].w;
    }
    __syncthreads();
  }
  if (t < 16) {
    float* slot = partial + (size_t)(blockIdx.x & 31) * 64;
    atomicAdd(slot + t * 4 + 0, s[t].x);
    atomicAdd(slot + t * 4 + 1, s[t].y);
    atomicAdd(slot + t * 4 + 2, s[t].z);
    atomicAdd(slot + t * 4 + 3, s[t].w);
  }
}

__global__ __launch_bounds__(64) void mean_finish(const float* __restrict__ partial,
                                                  float* __restrict__ out, int n) {
  const int c = threadIdx.x;
  float s = 0.f;
  #pragma unroll
  for (int k = 0; k < 32; ++k) s += partial[k * 64 + c];
  out[c] = s / (float)n;
}

extern "C" void kernel_launch(void* const* d_in, const int* in_sizes, int n_in,
                              void* d_out, int out_size, void* d_ws, size_t ws_size,
                              hipStream_t stream) {
  const float* pose = (const float*)d_in[0];
  const float* w_pos = (const float*)d_in[1];
  const float* b_pos = (const float*)d_in[2];
  const float* w_fc  = (const float*)d_in[3];
  const float* b_fc  = (const float*)d_in[4];
  const float* w_g1  = (const float*)d_in[5];
  const float* b_g1  = (const float*)d_in[6];
  const float* w_g2  = (const float*)d_in[7];
  const float* b_g2  = (const float*)d_in[8];
  const float* w_g3  = (const float*)d_in[9];
  const float* b_g3  = (const float*)d_in[10];
  const int*   edges = (const int*)d_in[11];

  const int n = in_sizes[0] / 64;   // N_NODES
  const int E = in_sizes[11] / 2;   // N_EDGES
  const int* rows = edges;
  const int* cols = edges + E;

  char* p = (char*)d_ws;
  auto alloc = [&](size_t bytes) { char* q = p; p += (bytes + 255) & ~(size_t)255; return q; };
  int*   cnt     = (int*)  alloc((size_t)n * 4);
  int*   off     = (int*)  alloc((size_t)(n + 1) * 4);
  int*   bsums   = (int*)  alloc(1024 * 4);
  float* dis     = (float*)alloc((size_t)n * 4);
  float* partial = (float*)alloc(32 * 64 * 4);
  // packed weights: hi/lo each, frag-ordered ushorts (K/32 * C/16 * 64 * 8 elems)
  unsigned short* wp_pos_h = (unsigned short*)alloc(2 * 8 * 64 * 8 * 2);
  unsigned short* wp_pos_l = (unsigned short*)alloc(2 * 8 * 64 * 8 * 2);
  unsigned short* wp_fc_h  = (unsigned short*)alloc(4 * 8 * 64 * 8 * 2);
  unsigned short* wp_fc_l  = (unsigned short*)alloc(4 * 8 * 64 * 8 * 2);
  unsigned short* wp_g1_h  = (unsigned short*)alloc(4 * 8 * 64 * 8 * 2);
  unsigned short* wp_g1_l  = (unsigned short*)alloc(4 * 8 * 64 * 8 * 2);
  unsigned short* wp_g2_h  = (unsigned short*)alloc(4 * 8 * 64 * 8 * 2);
  unsigned short* wp_g2_l  = (unsigned short*)alloc(4 * 8 * 64 * 8 * 2);
  unsigned short* wp_g3_h  = (unsigned short*)alloc(4 * 4 * 64 * 8 * 2);
  unsigned short* wp_g3_l  = (unsigned short*)alloc(4 * 4 * 64 * 8 * 2);
  int*   csr     = (int*)  alloc((size_t)E * 4);
  float* bufA    = (float*)alloc((size_t)n * 128 * 4);
  float* bufB    = (float*)alloc((size_t)n * 128 * 4);

  const int e_blocks    = (E + 255) / 256;
  const int n_blocks    = (n + 255) / 256;
  const int s1_blocks   = (n + 1023) / 1024;
  const int gemm_blocks = (n + 63) / 64;
  const int g4_blocks   = (n + 7) / 8;
  const int gm_blocks   = (n + 15) / 16;

  // ---- weight packs (independent of everything else) ----
  pack_w<<<(1024 + 255) / 256, 256, 0, stream>>>(w_pos, wp_pos_h, wp_pos_l, 64, 128);
  pack_w<<<(2048 + 255) / 256, 256, 0, stream>>>(w_fc,  wp_fc_h,  wp_fc_l,  128, 128);
  pack_w<<<(2048 + 255) / 256, 256, 0, stream>>>(w_g1,  wp_g1_h,  wp_g1_l,  128, 128);
  pack_w<<<(2048 + 255) / 256, 256, 0, stream>>>(w_g2,  wp_g2_h,  wp_g2_l,  128, 128);
  pack_w<<<(1024 + 255) / 256, 256, 0, stream>>>(w_g3,  wp_g3_h,  wp_g3_l,  128, 64);

  // ---- CSR build ----
  hipMemsetAsync(cnt, 0, (size_t)n * 4, stream);
  hipMemsetAsync(partial, 0, 32 * 64 * 4, stream);
  cnt_accum<<<e_blocks, 256, 0, stream>>>(cols, cnt, E);
  scan1<<<s1_blocks, 256, 0, stream>>>(cnt, off, bsums, dis, n);
  scan2<<<1, 256, 0, stream>>>(bsums, s1_blocks);
  scan3<<<n_blocks, 256, 0, stream>>>(off, bsums, n, E);
  fill_csr<<<e_blocks, 256, 0, stream>>>(rows, cols, off, cnt, csr, E);

  // ---- refine ----
  gemm_mfma<64, 128, true, false, true><<<gemm_blocks, 256, 0, stream>>>(
      pose, wp_pos_h, wp_pos_l, b_pos, nullptr, bufA, n);
  gemm_mfma<128, 128, false, false, true><<<gemm_blocks, 256, 0, stream>>>(
      bufA, wp_fc_h, wp_fc_l, b_fc, nullptr, bufB, n);

  // ---- conv1 ----
  gemm_mfma<128, 128, false, true, false><<<gemm_blocks, 256, 0, stream>>>(
      bufB, wp_g1_h, wp_g1_l, nullptr, dis, bufA, n);
  gather4_kernel<128><<<g4_blocks, 256, 0, stream>>>(csr, off, bufA, dis, b_g1, bufB, n);

  // ---- conv2 ----
  gemm_mfma<128, 128, false, true, false><<<gemm_blocks, 256, 0, stream>>>(
      bufB, wp_g2_h, wp_g2_l, nullptr, dis, bufA, n);
  gather4_kernel<128><<<g4_blocks, 256, 0, stream>>>(csr, off, bufA, dis, b_g2, bufB, n);

  // ---- conv3 + mean ----
  gemm_mfma<128, 64, false, true, false><<<gemm_blocks, 256, 0, stream>>>(
      bufB, wp_g3_h, wp_g3_l, nullptr, dis, bufA, n);
  gather_mean_part<<<gm_blocks, 256, 0, stream>>>(csr, off, bufA, dis, b_g3, partial, n);
  mean_finish<<<1, 64, 0, stream>>>(partial, (float*)d_out, n);
}

// Round 6
// 562.198 us; speedup vs baseline: 12.8259x; 1.1053x over previous
//
#include <hip/hip_runtime.h>

#define SLOPE 0.01f

typedef __attribute__((ext_vector_type(8))) short short8;
typedef __attribute__((ext_vector_type(4))) float f32x4;

__device__ __forceinline__ float lrelu(float v) { return v >= 0.0f ? v : SLOPE * v; }

__device__ __forceinline__ unsigned short f2bf(float f) {
  unsigned int u = __float_as_uint(f);
  return (unsigned short)((u + 0x7FFF + ((u >> 16) & 1)) >> 16);
}
__device__ __forceinline__ float bf2f(unsigned short h) {
  return __uint_as_float(((unsigned int)h) << 16);
}

// ---------------- CSR build: counts + scan ----------------
__global__ __launch_bounds__(256) void cnt_accum(const int* __restrict__ cols,
                                                 int* __restrict__ cnt, int E) {
  int t = blockIdx.x * 256 + threadIdx.x;
  if (t < E) atomicAdd(&cnt[cols[t]], 1);
}

__global__ __launch_bounds__(256) void scan1(const int* __restrict__ cnt,
                                             int* __restrict__ off,
                                             int* __restrict__ bsums,
                                             float* __restrict__ dis, int n) {
  __shared__ int s[256];
  const int t = threadIdx.x;
  const int base = blockIdx.x * 1024 + t * 4;
  int c[4];
  #pragma unroll
  for (int j = 0; j < 4; ++j) { int i = base + j; c[j] = (i < n) ? cnt[i] : 0; }
  int tsum = c[0] + c[1] + c[2] + c[3];
  s[t] = tsum;
  __syncthreads();
  for (int d = 1; d < 256; d <<= 1) {
    int v = (t >= d) ? s[t - d] : 0;
    __syncthreads();
    s[t] += v;
    __syncthreads();
  }
  int run = s[t] - tsum;
  #pragma unroll
  for (int j = 0; j < 4; ++j) {
    int i = base + j;
    if (i < n) { off[i] = run; dis[i] = rsqrtf((float)c[j] + 1.0f); }
    run += c[j];
  }
  if (t == 255) bsums[blockIdx.x] = s[255];
}

__global__ __launch_bounds__(256) void scan2(int* __restrict__ bsums, int nb) {
  __shared__ int s[256];
  const int t = threadIdx.x;
  int v = (t < nb) ? bsums[t] : 0;
  s[t] = v;
  __syncthreads();
  for (int d = 1; d < 256; d <<= 1) {
    int u = (t >= d) ? s[t - d] : 0;
    __syncthreads();
    s[t] += u;
    __syncthreads();
  }
  if (t < nb) bsums[t] = s[t] - v;
}

__global__ __launch_bounds__(256) void scan3(int* __restrict__ off,
                                             const int* __restrict__ bsums, int n, int E) {
  int i = blockIdx.x * 256 + threadIdx.x;
  if (i < n) off[i] += bsums[i >> 10];
  if (i == 0) off[n] = E;
}

// ---------------- CSR fill pass A: LDS bucket-binning (512 cols / bucket) ----------------
// Each block: 4096 edges -> LDS histogram by bucket -> LDS bucket-sort ->
// per-bucket global cursor reservation -> coalesced run flush into tmp (int2 = col,row).
__global__ __launch_bounds__(256) void bin_pass(const int* __restrict__ rows,
                                                const int* __restrict__ cols,
                                                const int* __restrict__ off,
                                                int* __restrict__ gcur,
                                                int2* __restrict__ tmp,
                                                int E, int n, int NB) {
  __shared__ int hist[256];
  __shared__ int scanbuf[256];
  __shared__ int lstart[256];
  __shared__ int lcur[256];
  __shared__ int gbase[256];
  __shared__ int2 stage[4096];
  const int t = threadIdx.x;
  const int e0 = blockIdx.x * 4096;
  const int cnt = min(4096, E - e0);

  hist[t] = 0;
  __syncthreads();

  int ec[16], er[16];
  int m = 0;
  for (int i = t; i < cnt; i += 256) {
    int c = cols[e0 + i], r = rows[e0 + i];
    ec[m] = c; er[m] = r; ++m;
    atomicAdd(&hist[c >> 9], 1);
  }
  __syncthreads();

  // exclusive scan of hist -> lstart
  int v = hist[t];
  scanbuf[t] = v;
  __syncthreads();
  for (int d = 1; d < 256; d <<= 1) {
    int u = (t >= d) ? scanbuf[t - d] : 0;
    __syncthreads();
    scanbuf[t] += u;
    __syncthreads();
  }
  lstart[t] = scanbuf[t] - v;
  lcur[t] = 0;
  __syncthreads();

  for (int k = 0; k < m; ++k) {
    int b = ec[k] >> 9;
    int p = lstart[b] + atomicAdd(&lcur[b], 1);
    stage[p] = make_int2(ec[k], er[k]);
  }
  __syncthreads();

  if (t < NB && hist[t] > 0) {
    gbase[t] = off[t << 9] + atomicAdd(&gcur[t], hist[t]);
  }
  __syncthreads();

  for (int i = t; i < cnt; i += 256) {
    int2 pr = stage[i];
    int b = pr.x >> 9;
    tmp[gbase[b] + (i - lstart[b])] = pr;
  }
}

// ---------------- CSR fill pass B: per-bucket LDS scatter + contiguous flush ----------------
__global__ __launch_bounds__(256) void bucket_csr(const int2* __restrict__ tmp,
                                                  const int* __restrict__ off,
                                                  int* __restrict__ csr, int n) {
  const int b = blockIdx.x;
  const int c0 = b << 9;
  const int c1 = min(c0 + 512, n);
  const int ncols = c1 - c0;
  __shared__ int lofs[513];
  __shared__ int lcur[512];
  __shared__ int img[12288];
  const int t = threadIdx.x;
  const int base = off[c0];
  for (int i = t; i <= ncols; i += 256) lofs[i] = off[c0 + i] - base;
  for (int i = t; i < 512; i += 256) lcur[i] = 0;
  __syncthreads();
  const int bcnt = lofs[ncols];
  if (bcnt <= 12288) {
    for (int i = t; i < bcnt; i += 256) {
      int2 p = tmp[base + i];
      int lc = p.x - c0;
      int pos = atomicAdd(&lcur[lc], 1);
      img[lofs[lc] + pos] = p.y;
    }
    __syncthreads();
    for (int i = t; i < bcnt; i += 256) csr[base + i] = img[i];
  } else {  // astronomically unlikely overflow fallback
    for (int i = t; i < bcnt; i += 256) {
      int2 p = tmp[base + i];
      int lc = p.x - c0;
      int pos = atomicAdd(&lcur[lc], 1);
      csr[base + lofs[lc] + pos] = p.y;
    }
  }
}

// ---------------- W pack: fragment-ordered bf16 hi/lo ----------------
__global__ __launch_bounds__(256) void pack_w(const float* __restrict__ W,
                                              unsigned short* __restrict__ hi,
                                              unsigned short* __restrict__ lo,
                                              int K, int C) {
  const int KS = K / 32, CT = C / 16;
  int t = blockIdx.x * 256 + threadIdx.x;
  int total = CT * KS * 64;
  if (t >= total) return;
  int l = t & 63;
  int rest = t >> 6;
  int ks = rest % KS;
  int ct = rest / KS;
  int k0 = ks * 32 + (l >> 4) * 8;
  int c  = ct * 16 + (l & 15);
  short8 hv, lv;
  #pragma unroll
  for (int b = 0; b < 8; ++b) {
    float v = W[(size_t)(k0 + b) * C + c];
    unsigned short h = f2bf(v);
    hv[b] = (short)h;
    lv[b] = (short)f2bf(v - bf2f(h));
  }
  ((short8*)hi)[t] = hv;
  ((short8*)lo)[t] = lv;
}

// ---------------- MFMA GEMM (bf16x3) ----------------
template<int K, int C, bool ACT, bool SCALE, bool BIAS>
__global__ __launch_bounds__(256) void gemm_mfma(
    const float* __restrict__ x,
    const unsigned short* __restrict__ whi, const unsigned short* __restrict__ wlo,
    const float* __restrict__ bias, const float* __restrict__ rowscale,
    float* __restrict__ y, int n)
{
  constexpr int NC = C / 16;
  constexpr int KS = K / 32;
  const int t = threadIdx.x;
  const int w = t >> 6;
  const int lane = t & 63;
  const int row_base = blockIdx.x * 64 + w * 16;
  const int arow_raw = row_base + (lane & 15);
  const int arow = (arow_raw < n) ? arow_raw : 0;
  const int asub = (lane >> 4) * 8;
  const float* xrow = x + (size_t)arow * K + asub;

  f32x4 acc[NC];
  #pragma unroll
  for (int ct = 0; ct < NC; ++ct) acc[ct] = (f32x4){0.f, 0.f, 0.f, 0.f};

  const short8* WH = (const short8*)whi;
  const short8* WL = (const short8*)wlo;

  #pragma unroll
  for (int ks = 0; ks < KS; ++ks) {
    float4 v0 = *(const float4*)(xrow + ks * 32);
    float4 v1 = *(const float4*)(xrow + ks * 32 + 4);
    float xv[8] = {v0.x, v0.y, v0.z, v0.w, v1.x, v1.y, v1.z, v1.w};
    short8 ah, al;
    #pragma unroll
    for (int b = 0; b < 8; ++b) {
      unsigned short h = f2bf(xv[b]);
      ah[b] = (short)h;
      al[b] = (short)f2bf(xv[b] - bf2f(h));
    }
    #pragma unroll
    for (int ct = 0; ct < NC; ++ct) {
      short8 bh = WH[(ct * KS + ks) * 64 + lane];
      short8 bl = WL[(ct * KS + ks) * 64 + lane];
      acc[ct] = __builtin_amdgcn_mfma_f32_16x16x32_bf16(ah, bh, acc[ct], 0, 0, 0);
      acc[ct] = __builtin_amdgcn_mfma_f32_16x16x32_bf16(ah, bl, acc[ct], 0, 0, 0);
      acc[ct] = __builtin_amdgcn_mfma_f32_16x16x32_bf16(al, bh, acc[ct], 0, 0, 0);
    }
  }

  const int colb = lane & 15;
  const int rsub = (lane >> 4) * 4;
  float bcol[NC];
  #pragma unroll
  for (int ct = 0; ct < NC; ++ct) bcol[ct] = BIAS ? bias[ct * 16 + colb] : 0.f;

  #pragma unroll
  for (int r = 0; r < 4; ++r) {
    int row = row_base + rsub + r;
    if (row >= n) continue;
    float sc = SCALE ? rowscale[row] : 1.0f;
    #pragma unroll
    for (int ct = 0; ct < NC; ++ct) {
      float v = acc[ct][r];
      if (BIAS) v += bcol[ct];
      if (SCALE) v *= sc;
      if (ACT) v = lrelu(v);
      y[(size_t)row * C + ct * 16 + colb] = v;
    }
  }
}

// ---------------- fused gather (float4 + shfl-broadcast csr, unroll 8) ----------------
template<int C>
__global__ __launch_bounds__(256) void gather4_kernel(
    const int* __restrict__ csr, const int* __restrict__ off,
    const float* __restrict__ hs, const float* __restrict__ dis,
    const float* __restrict__ bias, float* __restrict__ y, int n)
{
  constexpr int GPN = C / 4;
  constexpr int NPB = 256 / GPN;
  const int t = threadIdx.x;
  const int l = t % GPN;
  const int node = blockIdx.x * NPB + t / GPN;
  if (node >= n) return;
  const int o = off[node];
  const int d = off[node + 1] - o;

  float4 acc = make_float4(0.f, 0.f, 0.f, 0.f);
  for (int base = 0; base < d; base += GPN) {
    const int batch = min(d - base, GPN);
    int idx = (l < batch) ? csr[o + base + l] : 0;
    int j = 0;
    for (; j + 8 <= batch; j += 8) {
      float4 a[8];
      #pragma unroll
      for (int u = 0; u < 8; ++u) {
        int r = __shfl(idx, j + u, GPN);
        a[u] = *(const float4*)(hs + (size_t)r * C + l * 4);
      }
      #pragma unroll
      for (int u = 0; u < 8; u += 2) {
        acc.x += a[u].x + a[u + 1].x; acc.y += a[u].y + a[u + 1].y;
        acc.z += a[u].z + a[u + 1].z; acc.w += a[u].w + a[u + 1].w;
      }
    }
    for (; j < batch; ++j) {
      int r = __shfl(idx, j, GPN);
      float4 a = *(const float4*)(hs + (size_t)r * C + l * 4);
      acc.x += a.x; acc.y += a.y; acc.z += a.z; acc.w += a.w;
    }
  }

  const float dd = dis[node];
  float4 h  = *(const float4*)(hs + (size_t)node * C + l * 4);
  float4 b4 = *(const float4*)(bias + l * 4);
  float4 out;
  out.x = lrelu((acc.x + h.x) * dd + b4.x);
  out.y = lrelu((acc.y + h.y) * dd + b4.y);
  out.z = lrelu((acc.z + h.z) * dd + b4.z);
  out.w = lrelu((acc.w + h.w) * dd + b4.w);
  *(float4*)(y + (size_t)node * C + l * 4) = out;
}

// ---------------- conv3: gather + finalize + block partial sums (C=64) ----------------
__global__ __launch_bounds__(256) void gather_mean_part(
    const int* __restrict__ csr, const int* __restrict__ off,
    const float* __restrict__ hs, const float* __restrict__ dis,
    const float* __restrict__ bias, float* __restrict__ partial, int n)
{
  constexpr int GPN = 16;
  const int t = threadIdx.x;
  const int l = t % GPN;
  const int node = blockIdx.x * 16 + t / GPN;
  float4 b4 = *(const float4*)(bias + l * 4);
  float4 val = make_float4(0.f, 0.f, 0.f, 0.f);

  if (node < n) {
    const int o = off[node];
    const int d = off[node + 1] - o;
    float4 acc = make_float4(0.f, 0.f, 0.f, 0.f);
    for (int base = 0; base < d; base += GPN) {
      const int batch = min(d - base, GPN);
      int idx = (l < batch) ? csr[o + base + l] : 0;
      int j = 0;
      for (; j + 8 <= batch; j += 8) {
        float4 a[8];
        #pragma unroll
        for (int u = 0; u < 8; ++u) {
          int r = __shfl(idx, j + u, GPN);
          a[u] = *(const float4*)(hs + (size_t)r * 64 + l * 4);
        }
        #pragma unroll
        for (int u = 0; u < 8; u += 2) {
          acc.x += a[u].x + a[u + 1].x; acc.y += a[u].y + a[u + 1].y;
          acc.z += a[u].z + a[u + 1].z; acc.w += a[u].w + a[u + 1].w;
        }
      }
      for (; j < batch; ++j) {
        int r = __shfl(idx, j, GPN);
        float4 a = *(const float4*)(hs + (size_t)r * 64 + l * 4);
        acc.x += a.x; acc.y += a.y; acc.z += a.z; acc.w += a.w;
      }
    }
    const float dd = dis[node];
    float4 h = *(const float4*)(hs + (size_t)node * 64 + l * 4);
    val.x = lrelu((acc.x + h.x) * dd + b4.x);
    val.y = lrelu((acc.y + h.y) * dd + b4.y);
    val.z = lrelu((acc.z + h.z) * dd + b4.z);
    val.w = lrelu((acc.w + h.w) * dd + b4.w);
  }

  __shared__ float4 s[256];
  s[t] = val;
  __syncthreads();
  for (int offst = 128; offst >= 16; offst >>= 1) {
    if (t < offst) {
      s[t].x += s[t + offst].x; s[t].y += s[t + offst].y;
      s[t].z += s[t + offst].z; s[t].w += s[t + offst].w;
    }
    __syncthreads();
  }
  if (t < 16) {
    float* slot = partial + (size_t)(blockIdx.x & 31) * 64;
    atomicAdd(slot + t * 4 + 0, s[t].x);
    atomicAdd(slot + t * 4 + 1, s[t].y);
    atomicAdd(slot + t * 4 + 2, s[t].z);
    atomicAdd(slot + t * 4 + 3, s[t].w);
  }
}

__global__ __launch_bounds__(64) void mean_finish(const float* __restrict__ partial,
                                                  float* __restrict__ out, int n) {
  const int c = threadIdx.x;
  float s = 0.f;
  #pragma unroll
  for (int k = 0; k < 32; ++k) s += partial[k * 64 + c];
  out[c] = s / (float)n;
}

extern "C" void kernel_launch(void* const* d_in, const int* in_sizes, int n_in,
                              void* d_out, int out_size, void* d_ws, size_t ws_size,
                              hipStream_t stream) {
  const float* pose = (const float*)d_in[0];
  const float* w_pos = (const float*)d_in[1];
  const float* b_pos = (const float*)d_in[2];
  const float* w_fc  = (const float*)d_in[3];
  const float* b_fc  = (const float*)d_in[4];
  const float* w_g1  = (const float*)d_in[5];
  const float* b_g1  = (const float*)d_in[6];
  const float* w_g2  = (const float*)d_in[7];
  const float* b_g2  = (const float*)d_in[8];
  const float* w_g3  = (const float*)d_in[9];
  const float* b_g3  = (const float*)d_in[10];
  const int*   edges = (const int*)d_in[11];

  const int n = in_sizes[0] / 64;   // N_NODES
  const int E = in_sizes[11] / 2;   // N_EDGES
  const int* rows = edges;
  const int* cols = edges + E;
  const int NB = (n + 511) >> 9;    // col buckets (<=256 required; 196 for n=100k)

  char* p = (char*)d_ws;
  auto alloc = [&](size_t bytes) { char* q = p; p += (bytes + 255) & ~(size_t)255; return q; };
  int*   cnt     = (int*)  alloc((size_t)n * 4);
  int*   off     = (int*)  alloc((size_t)(n + 1) * 4);
  int*   bsums   = (int*)  alloc(1024 * 4);
  int*   gcur    = (int*)  alloc(256 * 4);
  float* dis     = (float*)alloc((size_t)n * 4);
  float* partial = (float*)alloc(32 * 64 * 4);
  unsigned short* wp_pos_h = (unsigned short*)alloc(2 * 8 * 64 * 8 * 2);
  unsigned short* wp_pos_l = (unsigned short*)alloc(2 * 8 * 64 * 8 * 2);
  unsigned short* wp_fc_h  = (unsigned short*)alloc(4 * 8 * 64 * 8 * 2);
  unsigned short* wp_fc_l  = (unsigned short*)alloc(4 * 8 * 64 * 8 * 2);
  unsigned short* wp_g1_h  = (unsigned short*)alloc(4 * 8 * 64 * 8 * 2);
  unsigned short* wp_g1_l  = (unsigned short*)alloc(4 * 8 * 64 * 8 * 2);
  unsigned short* wp_g2_h  = (unsigned short*)alloc(4 * 8 * 64 * 8 * 2);
  unsigned short* wp_g2_l  = (unsigned short*)alloc(4 * 8 * 64 * 8 * 2);
  unsigned short* wp_g3_h  = (unsigned short*)alloc(4 * 4 * 64 * 8 * 2);
  unsigned short* wp_g3_l  = (unsigned short*)alloc(4 * 4 * 64 * 8 * 2);
  int*   csr     = (int*)  alloc((size_t)E * 4);
  float* bufA    = (float*)alloc((size_t)n * 128 * 4);
  float* bufB    = (float*)alloc((size_t)n * 128 * 4);
  // tmp (E int2 pairs, 12.8 MB) aliases bufA: consumed by bucket_csr before any GEMM writes bufA
  int2*  tmp     = (int2*)bufA;

  const int e_blocks    = (E + 255) / 256;
  const int n_blocks    = (n + 255) / 256;
  const int s1_blocks   = (n + 1023) / 1024;
  const int bin_blocks  = (E + 4095) / 4096;
  const int gemm_blocks = (n + 63) / 64;
  const int g4_blocks   = (n + 7) / 8;
  const int gm_blocks   = (n + 15) / 16;

  // ---- weight packs ----
  pack_w<<<(1024 + 255) / 256, 256, 0, stream>>>(w_pos, wp_pos_h, wp_pos_l, 64, 128);
  pack_w<<<(2048 + 255) / 256, 256, 0, stream>>>(w_fc,  wp_fc_h,  wp_fc_l,  128, 128);
  pack_w<<<(2048 + 255) / 256, 256, 0, stream>>>(w_g1,  wp_g1_h,  wp_g1_l,  128, 128);
  pack_w<<<(2048 + 255) / 256, 256, 0, stream>>>(w_g2,  wp_g2_h,  wp_g2_l,  128, 128);
  pack_w<<<(1024 + 255) / 256, 256, 0, stream>>>(w_g3,  wp_g3_h,  wp_g3_l,  128, 64);

  // ---- CSR build ----
  hipMemsetAsync(cnt, 0, (size_t)n * 4, stream);
  hipMemsetAsync(gcur, 0, 256 * 4, stream);
  hipMemsetAsync(partial, 0, 32 * 64 * 4, stream);
  cnt_accum<<<e_blocks, 256, 0, stream>>>(cols, cnt, E);
  scan1<<<s1_blocks, 256, 0, stream>>>(cnt, off, bsums, dis, n);
  scan2<<<1, 256, 0, stream>>>(bsums, s1_blocks);
  scan3<<<n_blocks, 256, 0, stream>>>(off, bsums, n, E);
  bin_pass<<<bin_blocks, 256, 0, stream>>>(rows, cols, off, gcur, tmp, E, n, NB);
  bucket_csr<<<NB, 256, 0, stream>>>(tmp, off, csr, n);

  // ---- refine ----
  gemm_mfma<64, 128, true, false, true><<<gemm_blocks, 256, 0, stream>>>(
      pose, wp_pos_h, wp_pos_l, b_pos, nullptr, bufA, n);
  gemm_mfma<128, 128, false, false, true><<<gemm_blocks, 256, 0, stream>>>(
      bufA, wp_fc_h, wp_fc_l, b_fc, nullptr, bufB, n);

  // ---- conv1 ----
  gemm_mfma<128, 128, false, true, false><<<gemm_blocks, 256, 0, stream>>>(
      bufB, wp_g1_h, wp_g1_l, nullptr, dis, bufA, n);
  gather4_kernel<128><<<g4_blocks, 256, 0, stream>>>(csr, off, bufA, dis, b_g1, bufB, n);

  // ---- conv2 ----
  gemm_mfma<128, 128, false, true, false><<<gemm_blocks, 256, 0, stream>>>(
      bufB, wp_g2_h, wp_g2_l, nullptr, dis, bufA, n);
  gather4_kernel<128><<<g4_blocks, 256, 0, stream>>>(csr, off, bufA, dis, b_g2, bufB, n);

  // ---- conv3 + mean ----
  gemm_mfma<128, 64, false, true, false><<<gemm_blocks, 256, 0, stream>>>(
      bufB, wp_g3_h, wp_g3_l, nullptr, dis, bufA, n);
  gather_mean_part<<<gm_blocks, 256, 0, stream>>>(csr, off, bufA, dis, b_g3, partial, n);
  mean_finish<<<1, 64, 0, stream>>>(partial, (float*)d_out, n);
}

// Round 7
// 482.697 us; speedup vs baseline: 14.9383x; 1.1647x over previous
//
#include <hip/hip_runtime.h>

#define SLOPE 0.01f

typedef __attribute__((ext_vector_type(8))) short short8;
typedef __attribute__((ext_vector_type(4))) float f32x4;

__device__ __forceinline__ float lrelu(float v) { return v >= 0.0f ? v : SLOPE * v; }

__device__ __forceinline__ unsigned short f2bf(float f) {
  unsigned int u = __float_as_uint(f);
  return (unsigned short)((u + 0x7FFF + ((u >> 16) & 1)) >> 16);
}
__device__ __forceinline__ float bf2f(unsigned short h) {
  return __uint_as_float(((unsigned int)h) << 16);
}

// ---------------- CSR: bucket totals (512 cols per bucket) ----------------
__global__ __launch_bounds__(256) void bucket_cnt(const int* __restrict__ cols,
                                                  int* __restrict__ btot, int E, int NB) {
  __shared__ int h[256];
  const int t = threadIdx.x;
  const int e0 = blockIdx.x * 4096;
  const int end = min(e0 + 4096, E);
  h[t] = 0;
  __syncthreads();
  for (int i = e0 + t; i < end; i += 256) atomicAdd(&h[cols[i] >> 9], 1);
  __syncthreads();
  if (t < NB && h[t]) atomicAdd(&btot[t], h[t]);
}

__global__ __launch_bounds__(256) void scan_buckets(const int* __restrict__ btot,
                                                    int* __restrict__ bbase, int NB) {
  __shared__ int s[256];
  const int t = threadIdx.x;
  int v = (t < NB) ? btot[t] : 0;
  s[t] = v;
  __syncthreads();
  for (int d = 1; d < 256; d <<= 1) {
    int u = (t >= d) ? s[t - d] : 0;
    __syncthreads();
    s[t] += u;
    __syncthreads();
  }
  bbase[t] = s[t] - v;   // exclusive; bbase[NB] = E (btot[>=NB]=0)
}

// ---------------- CSR fill pass A: LDS bucket-binning ----------------
__global__ __launch_bounds__(256) void bin_pass(const int* __restrict__ rows,
                                                const int* __restrict__ cols,
                                                const int* __restrict__ bbase,
                                                int* __restrict__ gcur,
                                                int2* __restrict__ tmp,
                                                int E, int NB) {
  __shared__ int hist[256];
  __shared__ int scanbuf[256];
  __shared__ int lstart[256];
  __shared__ int lcur[256];
  __shared__ int gbase[256];
  __shared__ int2 stage[4096];
  const int t = threadIdx.x;
  const int e0 = blockIdx.x * 4096;
  const int cnt = min(4096, E - e0);

  hist[t] = 0;
  __syncthreads();

  int ec[16], er[16];
  int m = 0;
  for (int i = t; i < cnt; i += 256) {
    int c = cols[e0 + i], r = rows[e0 + i];
    ec[m] = c; er[m] = r; ++m;
    atomicAdd(&hist[c >> 9], 1);
  }
  __syncthreads();

  int v = hist[t];
  scanbuf[t] = v;
  __syncthreads();
  for (int d = 1; d < 256; d <<= 1) {
    int u = (t >= d) ? scanbuf[t - d] : 0;
    __syncthreads();
    scanbuf[t] += u;
    __syncthreads();
  }
  lstart[t] = scanbuf[t] - v;
  lcur[t] = 0;
  __syncthreads();

  for (int k = 0; k < m; ++k) {
    int b = ec[k] >> 9;
    int p = lstart[b] + atomicAdd(&lcur[b], 1);
    stage[p] = make_int2(ec[k], er[k]);
  }
  __syncthreads();

  if (t < NB && hist[t] > 0) {
    gbase[t] = bbase[t] + atomicAdd(&gcur[t], hist[t]);
  }
  __syncthreads();

  for (int i = t; i < cnt; i += 256) {
    int2 pr = stage[i];
    int b = pr.x >> 9;
    tmp[gbase[b] + (i - lstart[b])] = pr;
  }
}

// ---------------- CSR pass B: per-bucket hist + scan + scatter + flush ----------------
// Also produces off[], dis[] (degree) for its column range.
__global__ __launch_bounds__(256) void bucket_csr(const int2* __restrict__ tmp,
                                                  const int* __restrict__ bbase,
                                                  int* __restrict__ off,
                                                  float* __restrict__ dis,
                                                  int* __restrict__ csr, int n, int NB) {
  const int b = blockIdx.x;
  const int c0 = b << 9;
  const int ncols = min(512, n - c0);
  __shared__ int hist[512];
  __shared__ int scanbuf[256];
  __shared__ int lofs[513];
  __shared__ int lcur[512];
  __shared__ int img[12288];
  const int t = threadIdx.x;
  const int base = bbase[b];
  const int bcnt = bbase[b + 1] - base;

  for (int i = t; i < 512; i += 256) { hist[i] = 0; lcur[i] = 0; }
  __syncthreads();
  for (int i = t; i < bcnt; i += 256) {
    int2 p = tmp[base + i];
    atomicAdd(&hist[p.x - c0], 1);
  }
  __syncthreads();

  // exclusive scan of 512 (2 per thread)
  int a0 = hist[2 * t], a1 = hist[2 * t + 1];
  int v = a0 + a1;
  scanbuf[t] = v;
  __syncthreads();
  for (int d = 1; d < 256; d <<= 1) {
    int u = (t >= d) ? scanbuf[t - d] : 0;
    __syncthreads();
    scanbuf[t] += u;
    __syncthreads();
  }
  int ex = scanbuf[t] - v;
  lofs[2 * t] = ex;
  lofs[2 * t + 1] = ex + a0;
  __syncthreads();

  for (int i = t; i < ncols; i += 256) {
    off[c0 + i] = base + lofs[i];
    dis[c0 + i] = rsqrtf((float)hist[i] + 1.0f);
  }
  if (b == NB - 1 && t == 0) off[n] = base + bcnt;

  if (bcnt <= 12288) {
    for (int i = t; i < bcnt; i += 256) {
      int2 p = tmp[base + i];
      int lc = p.x - c0;
      int pos = atomicAdd(&lcur[lc], 1);
      img[lofs[lc] + pos] = p.y;
    }
    __syncthreads();
    for (int i = t; i < bcnt; i += 256) csr[base + i] = img[i];
  } else {  // overflow fallback (astronomically unlikely)
    for (int i = t; i < bcnt; i += 256) {
      int2 p = tmp[base + i];
      int lc = p.x - c0;
      int pos = atomicAdd(&lcur[lc], 1);
      csr[base + lofs[lc] + pos] = p.y;
    }
  }
}

// ---------------- W pack: fragment-ordered bf16 hi/lo ----------------
__global__ __launch_bounds__(256) void pack_w(const float* __restrict__ W,
                                              unsigned short* __restrict__ hi,
                                              unsigned short* __restrict__ lo,
                                              int K, int C) {
  const int KS = K / 32, CT = C / 16;
  int t = blockIdx.x * 256 + threadIdx.x;
  int total = CT * KS * 64;
  if (t >= total) return;
  int l = t & 63;
  int rest = t >> 6;
  int ks = rest % KS;
  int ct = rest / KS;
  int k0 = ks * 32 + (l >> 4) * 8;
  int c  = ct * 16 + (l & 15);
  short8 hv, lv;
  #pragma unroll
  for (int b = 0; b < 8; ++b) {
    float v = W[(size_t)(k0 + b) * C + c];
    unsigned short h = f2bf(v);
    hv[b] = (short)h;
    lv[b] = (short)f2bf(v - bf2f(h));
  }
  ((short8*)hi)[t] = hv;
  ((short8*)lo)[t] = lv;
}

// ---------------- MFMA GEMM (bf16x3) ----------------
template<int K, int C, bool ACT, bool SCALE, bool BIAS>
__global__ __launch_bounds__(256) void gemm_mfma(
    const float* __restrict__ x,
    const unsigned short* __restrict__ whi, const unsigned short* __restrict__ wlo,
    const float* __restrict__ bias, const float* __restrict__ rowscale,
    float* __restrict__ y, int n)
{
  constexpr int NC = C / 16;
  constexpr int KS = K / 32;
  const int t = threadIdx.x;
  const int w = t >> 6;
  const int lane = t & 63;
  const int row_base = blockIdx.x * 64 + w * 16;
  const int arow_raw = row_base + (lane & 15);
  const int arow = (arow_raw < n) ? arow_raw : 0;
  const int asub = (lane >> 4) * 8;
  const float* xrow = x + (size_t)arow * K + asub;

  f32x4 acc[NC];
  #pragma unroll
  for (int ct = 0; ct < NC; ++ct) acc[ct] = (f32x4){0.f, 0.f, 0.f, 0.f};

  const short8* WH = (const short8*)whi;
  const short8* WL = (const short8*)wlo;

  #pragma unroll
  for (int ks = 0; ks < KS; ++ks) {
    float4 v0 = *(const float4*)(xrow + ks * 32);
    float4 v1 = *(const float4*)(xrow + ks * 32 + 4);
    float xv[8] = {v0.x, v0.y, v0.z, v0.w, v1.x, v1.y, v1.z, v1.w};
    short8 ah, al;
    #pragma unroll
    for (int b = 0; b < 8; ++b) {
      unsigned short h = f2bf(xv[b]);
      ah[b] = (short)h;
      al[b] = (short)f2bf(xv[b] - bf2f(h));
    }
    #pragma unroll
    for (int ct = 0; ct < NC; ++ct) {
      short8 bh = WH[(ct * KS + ks) * 64 + lane];
      short8 bl = WL[(ct * KS + ks) * 64 + lane];
      acc[ct] = __builtin_amdgcn_mfma_f32_16x16x32_bf16(ah, bh, acc[ct], 0, 0, 0);
      acc[ct] = __builtin_amdgcn_mfma_f32_16x16x32_bf16(ah, bl, acc[ct], 0, 0, 0);
      acc[ct] = __builtin_amdgcn_mfma_f32_16x16x32_bf16(al, bh, acc[ct], 0, 0, 0);
    }
  }

  const int colb = lane & 15;
  const int rsub = (lane >> 4) * 4;
  float bcol[NC];
  #pragma unroll
  for (int ct = 0; ct < NC; ++ct) bcol[ct] = BIAS ? bias[ct * 16 + colb] : 0.f;

  #pragma unroll
  for (int r = 0; r < 4; ++r) {
    int row = row_base + rsub + r;
    if (row >= n) continue;
    float sc = SCALE ? rowscale[row] : 1.0f;
    #pragma unroll
    for (int ct = 0; ct < NC; ++ct) {
      float v = acc[ct][r];
      if (BIAS) v += bcol[ct];
      if (SCALE) v *= sc;
      if (ACT) v = lrelu(v);
      y[(size_t)row * C + ct * 16 + colb] = v;
    }
  }
}

// ---------------- fused refine: x2 = lrelu(pose@Wpos+b)@Wfc + bfc ----------------
__global__ __launch_bounds__(256) void refine_fused(
    const float* __restrict__ pose,
    const unsigned short* __restrict__ wph, const unsigned short* __restrict__ wpl,
    const float* __restrict__ b_pos,
    const unsigned short* __restrict__ wfh, const unsigned short* __restrict__ wfl,
    const float* __restrict__ b_fc,
    float* __restrict__ y, int n)
{
  __shared__ float x1s[4][16][132];
  const int t = threadIdx.x;
  const int w = t >> 6;
  const int lane = t & 63;
  const int row_base = blockIdx.x * 64 + w * 16;
  const int colb = lane & 15;
  const int rsub = (lane >> 4) * 4;
  const int asub = (lane >> 4) * 8;

  // ---- stage 1: K=64 -> C=128, act ----
  {
    const int arow_raw = row_base + (lane & 15);
    const int arow = (arow_raw < n) ? arow_raw : 0;
    const float* xrow = pose + (size_t)arow * 64 + asub;
    f32x4 acc[8];
    #pragma unroll
    for (int ct = 0; ct < 8; ++ct) acc[ct] = (f32x4){0.f, 0.f, 0.f, 0.f};
    const short8* WH = (const short8*)wph;
    const short8* WL = (const short8*)wpl;
    #pragma unroll
    for (int ks = 0; ks < 2; ++ks) {
      float4 v0 = *(const float4*)(xrow + ks * 32);
      float4 v1 = *(const float4*)(xrow + ks * 32 + 4);
      float xv[8] = {v0.x, v0.y, v0.z, v0.w, v1.x, v1.y, v1.z, v1.w};
      short8 ah, al;
      #pragma unroll
      for (int b = 0; b < 8; ++b) {
        unsigned short h = f2bf(xv[b]);
        ah[b] = (short)h;
        al[b] = (short)f2bf(xv[b] - bf2f(h));
      }
      #pragma unroll
      for (int ct = 0; ct < 8; ++ct) {
        short8 bh = WH[(ct * 2 + ks) * 64 + lane];
        short8 bl = WL[(ct * 2 + ks) * 64 + lane];
        acc[ct] = __builtin_amdgcn_mfma_f32_16x16x32_bf16(ah, bh, acc[ct], 0, 0, 0);
        acc[ct] = __builtin_amdgcn_mfma_f32_16x16x32_bf16(ah, bl, acc[ct], 0, 0, 0);
        acc[ct] = __builtin_amdgcn_mfma_f32_16x16x32_bf16(al, bh, acc[ct], 0, 0, 0);
      }
    }
    #pragma unroll
    for (int ct = 0; ct < 8; ++ct) {
      float bb = b_pos[ct * 16 + colb];
      #pragma unroll
      for (int r = 0; r < 4; ++r)
        x1s[w][rsub + r][ct * 16 + colb] = lrelu(acc[ct][r] + bb);
    }
  }
  __syncthreads();

  // ---- stage 2: K=128 -> C=128 ----
  {
    f32x4 acc[8];
    #pragma unroll
    for (int ct = 0; ct < 8; ++ct) acc[ct] = (f32x4){0.f, 0.f, 0.f, 0.f};
    const short8* WH = (const short8*)wfh;
    const short8* WL = (const short8*)wfl;
    const float* x1row = &x1s[w][lane & 15][0];
    #pragma unroll
    for (int ks = 0; ks < 4; ++ks) {
      float4 v0 = *(const float4*)(x1row + ks * 32 + asub);
      float4 v1 = *(const float4*)(x1row + ks * 32 + asub + 4);
      float xv[8] = {v0.x, v0.y, v0.z, v0.w, v1.x, v1.y, v1.z, v1.w};
      short8 ah, al;
      #pragma unroll
      for (int b = 0; b < 8; ++b) {
        unsigned short h = f2bf(xv[b]);
        ah[b] = (short)h;
        al[b] = (short)f2bf(xv[b] - bf2f(h));
      }
      #pragma unroll
      for (int ct = 0; ct < 8; ++ct) {
        short8 bh = WH[(ct * 4 + ks) * 64 + lane];
        short8 bl = WL[(ct * 4 + ks) * 64 + lane];
        acc[ct] = __builtin_amdgcn_mfma_f32_16x16x32_bf16(ah, bh, acc[ct], 0, 0, 0);
        acc[ct] = __builtin_amdgcn_mfma_f32_16x16x32_bf16(ah, bl, acc[ct], 0, 0, 0);
        acc[ct] = __builtin_amdgcn_mfma_f32_16x16x32_bf16(al, bh, acc[ct], 0, 0, 0);
      }
    }
    #pragma unroll
    for (int r = 0; r < 4; ++r) {
      int row = row_base + rsub + r;
      if (row >= n) continue;
      #pragma unroll
      for (int ct = 0; ct < 8; ++ct)
        y[(size_t)row * 128 + ct * 16 + colb] = acc[ct][r] + b_fc[ct * 16 + colb];
    }
  }
}

// ---------------- gather burst helper ----------------
template<int U, int GPN, int C>
__device__ __forceinline__ void gulp(const float* __restrict__ hs, int idx, int j, int l,
                                     float4& acc) {
  float4 a[U];
  #pragma unroll
  for (int u = 0; u < U; ++u) {
    int r = __shfl(idx, j + u, GPN);
    a[u] = *(const float4*)(hs + (size_t)r * C + l * 4);
  }
  #pragma unroll
  for (int st = 1; st < U; st <<= 1)
    #pragma unroll
    for (int u = 0; u < U; u += 2 * st) {
      a[u].x += a[u + st].x; a[u].y += a[u + st].y;
      a[u].z += a[u + st].z; a[u].w += a[u + st].w;
    }
  acc.x += a[0].x; acc.y += a[0].y; acc.z += a[0].z; acc.w += a[0].w;
}

// ---------------- fused gather + self-loop + bias + lrelu (deep bursts) ----------------
template<int C>
__global__ __launch_bounds__(256) void gather4_kernel(
    const int* __restrict__ csr, const int* __restrict__ off,
    const float* __restrict__ hs, const float* __restrict__ dis,
    const float* __restrict__ bias, float* __restrict__ y, int n)
{
  constexpr int GPN = C / 4;
  constexpr int NPB = 256 / GPN;
  const int t = threadIdx.x;
  const int l = t % GPN;
  const int node = blockIdx.x * NPB + t / GPN;
  if (node >= n) return;
  const int o = off[node];
  const int d = off[node + 1] - o;
  const float dd = dis[node];
  float4 h  = *(const float4*)(hs + (size_t)node * C + l * 4);
  float4 b4 = *(const float4*)(bias + l * 4);

  float4 acc = make_float4(0.f, 0.f, 0.f, 0.f);
  for (int base = 0; base < d; base += GPN) {
    const int batch = min(d - base, GPN);
    int idx = (l < batch) ? csr[o + base + l] : 0;
    int j = 0;
    for (; j + 16 <= batch; j += 16) gulp<16, GPN, C>(hs, idx, j, l, acc);
    if (j + 8 <= batch) { gulp<8, GPN, C>(hs, idx, j, l, acc); j += 8; }
    if (j + 4 <= batch) { gulp<4, GPN, C>(hs, idx, j, l, acc); j += 4; }
    for (; j < batch; ++j) {
      int r = __shfl(idx, j, GPN);
      float4 a = *(const float4*)(hs + (size_t)r * C + l * 4);
      acc.x += a.x; acc.y += a.y; acc.z += a.z; acc.w += a.w;
    }
  }

  float4 out;
  out.x = lrelu((acc.x + h.x) * dd + b4.x);
  out.y = lrelu((acc.y + h.y) * dd + b4.y);
  out.z = lrelu((acc.z + h.z) * dd + b4.z);
  out.w = lrelu((acc.w + h.w) * dd + b4.w);
  *(float4*)(y + (size_t)node * C + l * 4) = out;
}

// ---------------- conv3: gather + finalize + block partial sums (C=64) ----------------
__global__ __launch_bounds__(256) void gather_mean_part(
    const int* __restrict__ csr, const int* __restrict__ off,
    const float* __restrict__ hs, const float* __restrict__ dis,
    const float* __restrict__ bias, float* __restrict__ partial, int n)
{
  constexpr int GPN = 16;
  const int t = threadIdx.x;
  const int l = t % GPN;
  const int node = blockIdx.x * 16 + t / GPN;
  float4 b4 = *(const float4*)(bias + l * 4);
  float4 val = make_float4(0.f, 0.f, 0.f, 0.f);

  if (node < n) {
    const int o = off[node];
    const int d = off[node + 1] - o;
    const float dd = dis[node];
    float4 h = *(const float4*)(hs + (size_t)node * 64 + l * 4);
    float4 acc = make_float4(0.f, 0.f, 0.f, 0.f);
    for (int base = 0; base < d; base += GPN) {
      const int batch = min(d - base, GPN);
      int idx = (l < batch) ? csr[o + base + l] : 0;
      int j = 0;
      for (; j + 16 <= batch; j += 16) gulp<16, GPN, 64>(hs, idx, j, l, acc);
      if (j + 8 <= batch) { gulp<8, GPN, 64>(hs, idx, j, l, acc); j += 8; }
      if (j + 4 <= batch) { gulp<4, GPN, 64>(hs, idx, j, l, acc); j += 4; }
      for (; j < batch; ++j) {
        int r = __shfl(idx, j, GPN);
        float4 a = *(const float4*)(hs + (size_t)r * 64 + l * 4);
        acc.x += a.x; acc.y += a.y; acc.z += a.z; acc.w += a.w;
      }
    }
    val.x = lrelu((acc.x + h.x) * dd + b4.x);
    val.y = lrelu((acc.y + h.y) * dd + b4.y);
    val.z = lrelu((acc.z + h.z) * dd + b4.z);
    val.w = lrelu((acc.w + h.w) * dd + b4.w);
  }

  __shared__ float4 s[256];
  s[t] = val;
  __syncthreads();
  for (int offst = 128; offst >= 16; offst >>= 1) {
    if (t < offst) {
      s[t].x += s[t + offst].x; s[t].y += s[t + offst].y;
      s[t].z += s[t + offst].z; s[t].w += s[t + offst].w;
    }
    __syncthreads();
  }
  if (t < 16) {
    float* slot = partial + (size_t)(blockIdx.x & 31) * 64;
    atomicAdd(slot + t * 4 + 0, s[t].x);
    atomicAdd(slot + t * 4 + 1, s[t].y);
    atomicAdd(slot + t * 4 + 2, s[t].z);
    atomicAdd(slot + t * 4 + 3, s[t].w);
  }
}

__global__ __launch_bounds__(64) void mean_finish(const float* __restrict__ partial,
                                                  float* __restrict__ out, int n) {
  const int c = threadIdx.x;
  float s = 0.f;
  #pragma unroll
  for (int k = 0; k < 32; ++k) s += partial[k * 64 + c];
  out[c] = s / (float)n;
}

extern "C" void kernel_launch(void* const* d_in, const int* in_sizes, int n_in,
                              void* d_out, int out_size, void* d_ws, size_t ws_size,
                              hipStream_t stream) {
  const float* pose = (const float*)d_in[0];
  const float* w_pos = (const float*)d_in[1];
  const float* b_pos = (const float*)d_in[2];
  const float* w_fc  = (const float*)d_in[3];
  const float* b_fc  = (const float*)d_in[4];
  const float* w_g1  = (const float*)d_in[5];
  const float* b_g1  = (const float*)d_in[6];
  const float* w_g2  = (const float*)d_in[7];
  const float* b_g2  = (const float*)d_in[8];
  const float* w_g3  = (const float*)d_in[9];
  const float* b_g3  = (const float*)d_in[10];
  const int*   edges = (const int*)d_in[11];

  const int n = in_sizes[0] / 64;   // N_NODES
  const int E = in_sizes[11] / 2;   // N_EDGES
  const int* rows = edges;
  const int* cols = edges + E;
  const int NB = (n + 511) >> 9;    // col buckets (<=256)

  char* p = (char*)d_ws;
  auto alloc = [&](size_t bytes) { char* q = p; p += (bytes + 255) & ~(size_t)255; return q; };
  int*   off     = (int*)  alloc((size_t)(n + 1) * 4);
  int*   btot    = (int*)  alloc(256 * 4);
  int*   bbase   = (int*)  alloc(257 * 4);
  int*   gcur    = (int*)  alloc(256 * 4);
  float* dis     = (float*)alloc((size_t)n * 4);
  float* partial = (float*)alloc(32 * 64 * 4);
  unsigned short* wp_pos_h = (unsigned short*)alloc(2 * 8 * 64 * 8 * 2);
  unsigned short* wp_pos_l = (unsigned short*)alloc(2 * 8 * 64 * 8 * 2);
  unsigned short* wp_fc_h  = (unsigned short*)alloc(4 * 8 * 64 * 8 * 2);
  unsigned short* wp_fc_l  = (unsigned short*)alloc(4 * 8 * 64 * 8 * 2);
  unsigned short* wp_g1_h  = (unsigned short*)alloc(4 * 8 * 64 * 8 * 2);
  unsigned short* wp_g1_l  = (unsigned short*)alloc(4 * 8 * 64 * 8 * 2);
  unsigned short* wp_g2_h  = (unsigned short*)alloc(4 * 8 * 64 * 8 * 2);
  unsigned short* wp_g2_l  = (unsigned short*)alloc(4 * 8 * 64 * 8 * 2);
  unsigned short* wp_g3_h  = (unsigned short*)alloc(4 * 4 * 64 * 8 * 2);
  unsigned short* wp_g3_l  = (unsigned short*)alloc(4 * 4 * 64 * 8 * 2);
  int*   csr     = (int*)  alloc((size_t)E * 4);
  float* bufA    = (float*)alloc((size_t)n * 128 * 4);
  float* bufB    = (float*)alloc((size_t)n * 128 * 4);
  // tmp (E int2, 12.8 MB) aliases bufA: consumed by bucket_csr before conv1 GEMM writes bufA
  int2*  tmp     = (int2*)bufA;

  const int eb4k        = (E + 4095) / 4096;
  const int gemm_blocks = (n + 63) / 64;
  const int g4_blocks   = (n + 7) / 8;
  const int gm_blocks   = (n + 15) / 16;

  // ---- weight packs ----
  pack_w<<<(1024 + 255) / 256, 256, 0, stream>>>(w_pos, wp_pos_h, wp_pos_l, 64, 128);
  pack_w<<<(2048 + 255) / 256, 256, 0, stream>>>(w_fc,  wp_fc_h,  wp_fc_l,  128, 128);
  pack_w<<<(2048 + 255) / 256, 256, 0, stream>>>(w_g1,  wp_g1_h,  wp_g1_l,  128, 128);
  pack_w<<<(2048 + 255) / 256, 256, 0, stream>>>(w_g2,  wp_g2_h,  wp_g2_l,  128, 128);
  pack_w<<<(1024 + 255) / 256, 256, 0, stream>>>(w_g3,  wp_g3_h,  wp_g3_l,  128, 64);

  // ---- CSR build ----
  hipMemsetAsync(btot, 0, 256 * 4, stream);
  hipMemsetAsync(gcur, 0, 256 * 4, stream);
  hipMemsetAsync(partial, 0, 32 * 64 * 4, stream);
  bucket_cnt<<<eb4k, 256, 0, stream>>>(cols, btot, E, NB);
  scan_buckets<<<1, 256, 0, stream>>>(btot, bbase, NB);
  bin_pass<<<eb4k, 256, 0, stream>>>(rows, cols, bbase, gcur, tmp, E, NB);
  bucket_csr<<<NB, 256, 0, stream>>>(tmp, bbase, off, dis, csr, n, NB);

  // ---- refine (fused pair): pose -> bufB ----
  refine_fused<<<gemm_blocks, 256, 0, stream>>>(
      pose, wp_pos_h, wp_pos_l, b_pos, wp_fc_h, wp_fc_l, b_fc, bufB, n);

  // ---- conv1 ----
  gemm_mfma<128, 128, false, true, false><<<gemm_blocks, 256, 0, stream>>>(
      bufB, wp_g1_h, wp_g1_l, nullptr, dis, bufA, n);
  gather4_kernel<128><<<g4_blocks, 256, 0, stream>>>(csr, off, bufA, dis, b_g1, bufB, n);

  // ---- conv2 ----
  gemm_mfma<128, 128, false, true, false><<<gemm_blocks, 256, 0, stream>>>(
      bufB, wp_g2_h, wp_g2_l, nullptr, dis, bufA, n);
  gather4_kernel<128><<<g4_blocks, 256, 0, stream>>>(csr, off, bufA, dis, b_g2, bufB, n);

  // ---- conv3 + mean ----
  gemm_mfma<128, 64, false, true, false><<<gemm_blocks, 256, 0, stream>>>(
      bufB, wp_g3_h, wp_g3_l, nullptr, dis, bufA, n);
  gather_mean_part<<<gm_blocks, 256, 0, stream>>>(csr, off, bufA, dis, b_g3, partial, n);
  mean_finish<<<1, 64, 0, stream>>>(partial, (float*)d_out, n);
}

// Round 8
// 350.901 us; speedup vs baseline: 20.5490x; 1.3756x over previous
//
#include <hip/hip_runtime.h>

#define SLOPE 0.01f

typedef __attribute__((ext_vector_type(8))) short short8;
typedef __attribute__((ext_vector_type(4))) float f32x4;
typedef unsigned short u16;
typedef unsigned int u32;

__device__ __forceinline__ float lrelu(float v) { return v >= 0.0f ? v : SLOPE * v; }

__device__ __forceinline__ u16 f2bf(float f) {
  u32 u = __float_as_uint(f);
  return (u16)((u + 0x7FFF + ((u >> 16) & 1)) >> 16);
}
__device__ __forceinline__ float bf2f(u16 h) {
  return __uint_as_float(((u32)h) << 16);
}
__device__ __forceinline__ float bflo(u32 u) { return __uint_as_float(u << 16); }
__device__ __forceinline__ float bfhi(u32 u) { return __uint_as_float(u & 0xffff0000u); }

// ---------------- CSR: bucket totals (512 cols per bucket) ----------------
__global__ __launch_bounds__(256) void bucket_cnt(const int* __restrict__ cols,
                                                  int* __restrict__ btot, int E, int NB) {
  __shared__ int h[256];
  const int t = threadIdx.x;
  const int e0 = blockIdx.x * 4096;
  const int end = min(e0 + 4096, E);
  h[t] = 0;
  __syncthreads();
  for (int i = e0 + t; i < end; i += 256) atomicAdd(&h[cols[i] >> 9], 1);
  __syncthreads();
  if (t < NB && h[t]) atomicAdd(&btot[t], h[t]);
}

__global__ __launch_bounds__(256) void scan_buckets(const int* __restrict__ btot,
                                                    int* __restrict__ bbase, int NB) {
  __shared__ int s[256];
  const int t = threadIdx.x;
  int v = (t < NB) ? btot[t] : 0;
  s[t] = v;
  __syncthreads();
  for (int d = 1; d < 256; d <<= 1) {
    int u = (t >= d) ? s[t - d] : 0;
    __syncthreads();
    s[t] += u;
    __syncthreads();
  }
  bbase[t] = s[t] - v;
}

// ---------------- CSR fill pass A: LDS bucket-binning ----------------
__global__ __launch_bounds__(256) void bin_pass(const int* __restrict__ rows,
                                                const int* __restrict__ cols,
                                                const int* __restrict__ bbase,
                                                int* __restrict__ gcur,
                                                int2* __restrict__ tmp,
                                                int E, int NB) {
  __shared__ int hist[256];
  __shared__ int scanbuf[256];
  __shared__ int lstart[256];
  __shared__ int lcur[256];
  __shared__ int gbase[256];
  __shared__ int2 stage[4096];
  const int t = threadIdx.x;
  const int e0 = blockIdx.x * 4096;
  const int cnt = min(4096, E - e0);

  hist[t] = 0;
  __syncthreads();

  int ec[16], er[16];
  int m = 0;
  for (int i = t; i < cnt; i += 256) {
    int c = cols[e0 + i], r = rows[e0 + i];
    ec[m] = c; er[m] = r; ++m;
    atomicAdd(&hist[c >> 9], 1);
  }
  __syncthreads();

  int v = hist[t];
  scanbuf[t] = v;
  __syncthreads();
  for (int d = 1; d < 256; d <<= 1) {
    int u = (t >= d) ? scanbuf[t - d] : 0;
    __syncthreads();
    scanbuf[t] += u;
    __syncthreads();
  }
  lstart[t] = scanbuf[t] - v;
  lcur[t] = 0;
  __syncthreads();

  for (int k = 0; k < m; ++k) {
    int b = ec[k] >> 9;
    int p = lstart[b] + atomicAdd(&lcur[b], 1);
    stage[p] = make_int2(ec[k], er[k]);
  }
  __syncthreads();

  if (t < NB && hist[t] > 0) {
    gbase[t] = bbase[t] + atomicAdd(&gcur[t], hist[t]);
  }
  __syncthreads();

  for (int i = t; i < cnt; i += 256) {
    int2 pr = stage[i];
    int b = pr.x >> 9;
    tmp[gbase[b] + (i - lstart[b])] = pr;
  }
}

// ---------------- CSR pass B: per-bucket hist + scan + scatter + flush ----------------
__global__ __launch_bounds__(256) void bucket_csr(const int2* __restrict__ tmp,
                                                  const int* __restrict__ bbase,
                                                  int* __restrict__ off,
                                                  float* __restrict__ dis,
                                                  int* __restrict__ csr, int n, int NB) {
  const int b = blockIdx.x;
  const int c0 = b << 9;
  const int ncols = min(512, n - c0);
  __shared__ int hist[512];
  __shared__ int scanbuf[256];
  __shared__ int lofs[513];
  __shared__ int lcur[512];
  __shared__ int img[12288];
  const int t = threadIdx.x;
  const int base = bbase[b];
  const int bcnt = bbase[b + 1] - base;

  for (int i = t; i < 512; i += 256) { hist[i] = 0; lcur[i] = 0; }
  __syncthreads();
  for (int i = t; i < bcnt; i += 256) {
    int2 p = tmp[base + i];
    atomicAdd(&hist[p.x - c0], 1);
  }
  __syncthreads();

  int a0 = hist[2 * t], a1 = hist[2 * t + 1];
  int v = a0 + a1;
  scanbuf[t] = v;
  __syncthreads();
  for (int d = 1; d < 256; d <<= 1) {
    int u = (t >= d) ? scanbuf[t - d] : 0;
    __syncthreads();
    scanbuf[t] += u;
    __syncthreads();
  }
  int ex = scanbuf[t] - v;
  lofs[2 * t] = ex;
  lofs[2 * t + 1] = ex + a0;
  __syncthreads();

  for (int i = t; i < ncols; i += 256) {
    off[c0 + i] = base + lofs[i];
    dis[c0 + i] = rsqrtf((float)hist[i] + 1.0f);
  }
  if (b == NB - 1 && t == 0) off[n] = base + bcnt;

  if (bcnt <= 12288) {
    for (int i = t; i < bcnt; i += 256) {
      int2 p = tmp[base + i];
      int lc = p.x - c0;
      int pos = atomicAdd(&lcur[lc], 1);
      img[lofs[lc] + pos] = p.y;
    }
    __syncthreads();
    for (int i = t; i < bcnt; i += 256) csr[base + i] = img[i];
  } else {
    for (int i = t; i < bcnt; i += 256) {
      int2 p = tmp[base + i];
      int lc = p.x - c0;
      int pos = atomicAdd(&lcur[lc], 1);
      csr[base + lofs[lc] + pos] = p.y;
    }
  }
}

// ---------------- W pack: fragment-ordered bf16 hi/lo ----------------
__global__ __launch_bounds__(256) void pack_w(const float* __restrict__ W,
                                              u16* __restrict__ hi,
                                              u16* __restrict__ lo,
                                              int K, int C) {
  const int KS = K / 32, CT = C / 16;
  int t = blockIdx.x * 256 + threadIdx.x;
  int total = CT * KS * 64;
  if (t >= total) return;
  int l = t & 63;
  int rest = t >> 6;
  int ks = rest % KS;
  int ct = rest / KS;
  int k0 = ks * 32 + (l >> 4) * 8;
  int c  = ct * 16 + (l & 15);
  short8 hv, lv;
  #pragma unroll
  for (int b = 0; b < 8; ++b) {
    float v = W[(size_t)(k0 + b) * C + c];
    u16 h = f2bf(v);
    hv[b] = (short)h;
    lv[b] = (short)f2bf(v - bf2f(h));
  }
  ((short8*)hi)[t] = hv;
  ((short8*)lo)[t] = lv;
}

// ---------------- MFMA GEMM (bf16x3); OBF: write bf16 output ----------------
template<int K, int C, bool ACT, bool SCALE, bool BIAS, bool OBF>
__global__ __launch_bounds__(256) void gemm_mfma(
    const float* __restrict__ x,
    const u16* __restrict__ whi, const u16* __restrict__ wlo,
    const float* __restrict__ bias, const float* __restrict__ rowscale,
    void* __restrict__ yv, int n)
{
  constexpr int NC = C / 16;
  constexpr int KS = K / 32;
  const int t = threadIdx.x;
  const int w = t >> 6;
  const int lane = t & 63;
  const int row_base = blockIdx.x * 64 + w * 16;
  const int arow_raw = row_base + (lane & 15);
  const int arow = (arow_raw < n) ? arow_raw : 0;
  const int asub = (lane >> 4) * 8;
  const float* xrow = x + (size_t)arow * K + asub;

  f32x4 acc[NC];
  #pragma unroll
  for (int ct = 0; ct < NC; ++ct) acc[ct] = (f32x4){0.f, 0.f, 0.f, 0.f};

  const short8* WH = (const short8*)whi;
  const short8* WL = (const short8*)wlo;

  #pragma unroll
  for (int ks = 0; ks < KS; ++ks) {
    float4 v0 = *(const float4*)(xrow + ks * 32);
    float4 v1 = *(const float4*)(xrow + ks * 32 + 4);
    float xv[8] = {v0.x, v0.y, v0.z, v0.w, v1.x, v1.y, v1.z, v1.w};
    short8 ah, al;
    #pragma unroll
    for (int b = 0; b < 8; ++b) {
      u16 h = f2bf(xv[b]);
      ah[b] = (short)h;
      al[b] = (short)f2bf(xv[b] - bf2f(h));
    }
    #pragma unroll
    for (int ct = 0; ct < NC; ++ct) {
      short8 bh = WH[(ct * KS + ks) * 64 + lane];
      short8 bl = WL[(ct * KS + ks) * 64 + lane];
      acc[ct] = __builtin_amdgcn_mfma_f32_16x16x32_bf16(ah, bh, acc[ct], 0, 0, 0);
      acc[ct] = __builtin_amdgcn_mfma_f32_16x16x32_bf16(ah, bl, acc[ct], 0, 0, 0);
      acc[ct] = __builtin_amdgcn_mfma_f32_16x16x32_bf16(al, bh, acc[ct], 0, 0, 0);
    }
  }

  const int colb = lane & 15;
  const int rsub = (lane >> 4) * 4;
  float bcol[NC];
  #pragma unroll
  for (int ct = 0; ct < NC; ++ct) bcol[ct] = BIAS ? bias[ct * 16 + colb] : 0.f;

  #pragma unroll
  for (int r = 0; r < 4; ++r) {
    int row = row_base + rsub + r;
    if (row >= n) continue;
    float sc = SCALE ? rowscale[row] : 1.0f;
    #pragma unroll
    for (int ct = 0; ct < NC; ++ct) {
      float v = acc[ct][r];
      if (BIAS) v += bcol[ct];
      if (SCALE) v *= sc;
      if (ACT) v = lrelu(v);
      if (OBF) ((u16*)yv)[(size_t)row * C + ct * 16 + colb] = f2bf(v);
      else     ((float*)yv)[(size_t)row * C + ct * 16 + colb] = v;
    }
  }
}

// ---------------- fused refine: x2 = lrelu(pose@Wpos+b)@Wfc + bfc ----------------
__global__ __launch_bounds__(256) void refine_fused(
    const float* __restrict__ pose,
    const u16* __restrict__ wph, const u16* __restrict__ wpl,
    const float* __restrict__ b_pos,
    const u16* __restrict__ wfh, const u16* __restrict__ wfl,
    const float* __restrict__ b_fc,
    float* __restrict__ y, int n)
{
  __shared__ float x1s[4][16][132];
  const int t = threadIdx.x;
  const int w = t >> 6;
  const int lane = t & 63;
  const int row_base = blockIdx.x * 64 + w * 16;
  const int colb = lane & 15;
  const int rsub = (lane >> 4) * 4;
  const int asub = (lane >> 4) * 8;

  {
    const int arow_raw = row_base + (lane & 15);
    const int arow = (arow_raw < n) ? arow_raw : 0;
    const float* xrow = pose + (size_t)arow * 64 + asub;
    f32x4 acc[8];
    #pragma unroll
    for (int ct = 0; ct < 8; ++ct) acc[ct] = (f32x4){0.f, 0.f, 0.f, 0.f};
    const short8* WH = (const short8*)wph;
    const short8* WL = (const short8*)wpl;
    #pragma unroll
    for (int ks = 0; ks < 2; ++ks) {
      float4 v0 = *(const float4*)(xrow + ks * 32);
      float4 v1 = *(const float4*)(xrow + ks * 32 + 4);
      float xv[8] = {v0.x, v0.y, v0.z, v0.w, v1.x, v1.y, v1.z, v1.w};
      short8 ah, al;
      #pragma unroll
      for (int b = 0; b < 8; ++b) {
        u16 h = f2bf(xv[b]);
        ah[b] = (short)h;
        al[b] = (short)f2bf(xv[b] - bf2f(h));
      }
      #pragma unroll
      for (int ct = 0; ct < 8; ++ct) {
        short8 bh = WH[(ct * 2 + ks) * 64 + lane];
        short8 bl = WL[(ct * 2 + ks) * 64 + lane];
        acc[ct] = __builtin_amdgcn_mfma_f32_16x16x32_bf16(ah, bh, acc[ct], 0, 0, 0);
        acc[ct] = __builtin_amdgcn_mfma_f32_16x16x32_bf16(ah, bl, acc[ct], 0, 0, 0);
        acc[ct] = __builtin_amdgcn_mfma_f32_16x16x32_bf16(al, bh, acc[ct], 0, 0, 0);
      }
    }
    #pragma unroll
    for (int ct = 0; ct < 8; ++ct) {
      float bb = b_pos[ct * 16 + colb];
      #pragma unroll
      for (int r = 0; r < 4; ++r)
        x1s[w][rsub + r][ct * 16 + colb] = lrelu(acc[ct][r] + bb);
    }
  }
  __syncthreads();

  {
    f32x4 acc[8];
    #pragma unroll
    for (int ct = 0; ct < 8; ++ct) acc[ct] = (f32x4){0.f, 0.f, 0.f, 0.f};
    const short8* WH = (const short8*)wfh;
    const short8* WL = (const short8*)wfl;
    const float* x1row = &x1s[w][lane & 15][0];
    #pragma unroll
    for (int ks = 0; ks < 4; ++ks) {
      float4 v0 = *(const float4*)(x1row + ks * 32 + asub);
      float4 v1 = *(const float4*)(x1row + ks * 32 + asub + 4);
      float xv[8] = {v0.x, v0.y, v0.z, v0.w, v1.x, v1.y, v1.z, v1.w};
      short8 ah, al;
      #pragma unroll
      for (int b = 0; b < 8; ++b) {
        u16 h = f2bf(xv[b]);
        ah[b] = (short)h;
        al[b] = (short)f2bf(xv[b] - bf2f(h));
      }
      #pragma unroll
      for (int ct = 0; ct < 8; ++ct) {
        short8 bh = WH[(ct * 4 + ks) * 64 + lane];
        short8 bl = WL[(ct * 4 + ks) * 64 + lane];
        acc[ct] = __builtin_amdgcn_mfma_f32_16x16x32_bf16(ah, bh, acc[ct], 0, 0, 0);
        acc[ct] = __builtin_amdgcn_mfma_f32_16x16x32_bf16(ah, bl, acc[ct], 0, 0, 0);
        acc[ct] = __builtin_amdgcn_mfma_f32_16x16x32_bf16(al, bh, acc[ct], 0, 0, 0);
      }
    }
    #pragma unroll
    for (int r = 0; r < 4; ++r) {
      int row = row_base + rsub + r;
      if (row >= n) continue;
      #pragma unroll
      for (int ct = 0; ct < 8; ++ct)
        y[(size_t)row * 128 + ct * 16 + colb] = acc[ct][r] + b_fc[ct * 16 + colb];
    }
  }
}

// ---------------- bf16 gather bursts ----------------
template<int U>
__device__ __forceinline__ void gulp128b(const uint4* __restrict__ hsv, int idx, int j,
                                         int l, float* acc) {
  uint4 a[U];
  #pragma unroll
  for (int u = 0; u < U; ++u) {
    int r = __shfl(idx, j + u, 16);
    a[u] = hsv[(size_t)r * 16 + l];
  }
  #pragma unroll
  for (int u = 0; u < U; ++u) {
    acc[0] += bflo(a[u].x); acc[1] += bfhi(a[u].x);
    acc[2] += bflo(a[u].y); acc[3] += bfhi(a[u].y);
    acc[4] += bflo(a[u].z); acc[5] += bfhi(a[u].z);
    acc[6] += bflo(a[u].w); acc[7] += bfhi(a[u].w);
  }
}

template<int U>
__device__ __forceinline__ void gulp64b(const uint2* __restrict__ hsv, int idx, int j,
                                        int l, float* acc) {
  uint2 a[U];
  #pragma unroll
  for (int u = 0; u < U; ++u) {
    int r = __shfl(idx, j + u, 16);
    a[u] = hsv[(size_t)r * 16 + l];
  }
  #pragma unroll
  for (int u = 0; u < U; ++u) {
    acc[0] += bflo(a[u].x); acc[1] += bfhi(a[u].x);
    acc[2] += bflo(a[u].y); acc[3] += bfhi(a[u].y);
  }
}

// ---------------- gather (C=128, bf16 hs): 16 lanes/node, 8 cols/lane ----------------
__global__ __launch_bounds__(256) void gather_bf128(
    const int* __restrict__ csr, const int* __restrict__ off,
    const u16* __restrict__ hs, const float* __restrict__ dis,
    const float* __restrict__ bias, float* __restrict__ y, int n)
{
  const int t = threadIdx.x;
  const int l = t & 15;
  const int node = blockIdx.x * 16 + (t >> 4);
  if (node >= n) return;
  const int o = off[node];
  const int d = off[node + 1] - o;
  const float dd = dis[node];
  const uint4* hsv = (const uint4*)hs;   // row stride = 16 uint4 (128 cols bf16)

  // init acc with self-loop row
  uint4 hv = hsv[(size_t)node * 16 + l];
  float acc[8];
  acc[0] = bflo(hv.x); acc[1] = bfhi(hv.x);
  acc[2] = bflo(hv.y); acc[3] = bfhi(hv.y);
  acc[4] = bflo(hv.z); acc[5] = bfhi(hv.z);
  acc[6] = bflo(hv.w); acc[7] = bfhi(hv.w);

  for (int base = 0; base < d; base += 16) {
    const int batch = min(d - base, 16);
    int idx = (l < batch) ? csr[o + base + l] : 0;
    int j = 0;
    for (; j + 8 <= batch; j += 8) gulp128b<8>(hsv, idx, j, l, acc);
    if (j + 4 <= batch) { gulp128b<4>(hsv, idx, j, l, acc); j += 4; }
    for (; j < batch; ++j) gulp128b<1>(hsv, idx, j, l, acc);
  }

  float4 b0 = *(const float4*)(bias + l * 8);
  float4 b1 = *(const float4*)(bias + l * 8 + 4);
  float out[8];
  out[0] = lrelu(acc[0] * dd + b0.x); out[1] = lrelu(acc[1] * dd + b0.y);
  out[2] = lrelu(acc[2] * dd + b0.z); out[3] = lrelu(acc[3] * dd + b0.w);
  out[4] = lrelu(acc[4] * dd + b1.x); out[5] = lrelu(acc[5] * dd + b1.y);
  out[6] = lrelu(acc[6] * dd + b1.z); out[7] = lrelu(acc[7] * dd + b1.w);
  float* yp = y + (size_t)node * 128 + l * 8;
  *(float4*)yp       = make_float4(out[0], out[1], out[2], out[3]);
  *(float4*)(yp + 4) = make_float4(out[4], out[5], out[6], out[7]);
}

// ---------------- conv3: gather (C=64 bf16) + finalize + block partial sums ----------------
__global__ __launch_bounds__(256) void gather_mean_part(
    const int* __restrict__ csr, const int* __restrict__ off,
    const u16* __restrict__ hs, const float* __restrict__ dis,
    const float* __restrict__ bias, float* __restrict__ partial, int n)
{
  const int t = threadIdx.x;
  const int l = t & 15;
  const int node = blockIdx.x * 16 + (t >> 4);
  float4 b4 = *(const float4*)(bias + l * 4);
  float4 val = make_float4(0.f, 0.f, 0.f, 0.f);

  if (node < n) {
    const int o = off[node];
    const int d = off[node + 1] - o;
    const float dd = dis[node];
    const uint2* hsv = (const uint2*)hs;  // row stride = 16 uint2 (64 cols bf16)
    uint2 hv = hsv[(size_t)node * 16 + l];
    float acc[4];
    acc[0] = bflo(hv.x); acc[1] = bfhi(hv.x);
    acc[2] = bflo(hv.y); acc[3] = bfhi(hv.y);
    for (int base = 0; base < d; base += 16) {
      const int batch = min(d - base, 16);
      int idx = (l < batch) ? csr[o + base + l] : 0;
      int j = 0;
      for (; j + 8 <= batch; j += 8) gulp64b<8>(hsv, idx, j, l, acc);
      if (j + 4 <= batch) { gulp64b<4>(hsv, idx, j, l, acc); j += 4; }
      for (; j < batch; ++j) gulp64b<1>(hsv, idx, j, l, acc);
    }
    val.x = lrelu(acc[0] * dd + b4.x);
    val.y = lrelu(acc[1] * dd + b4.y);
    val.z = lrelu(acc[2] * dd + b4.z);
    val.w = lrelu(acc[3] * dd + b4.w);
  }

  __shared__ float4 s[256];
  s[t] = val;
  __syncthreads();
  for (int offst = 128; offst >= 16; offst >>= 1) {
    if (t < offst) {
      s[t].x += s[t + offst].x; s[t].y += s[t + offst].y;
      s[t].z += s[t + offst].z; s[t].w += s[t + offst].w;
    }
    __syncthreads();
  }
  if (t < 16) {
    float* slot = partial + (size_t)(blockIdx.x & 31) * 64;
    atomicAdd(slot + t * 4 + 0, s[t].x);
    atomicAdd(slot + t * 4 + 1, s[t].y);
    atomicAdd(slot + t * 4 + 2, s[t].z);
    atomicAdd(slot + t * 4 + 3, s[t].w);
  }
}

__global__ __launch_bounds__(64) void mean_finish(const float* __restrict__ partial,
                                                  float* __restrict__ out, int n) {
  const int c = threadIdx.x;
  float s = 0.f;
  #pragma unroll
  for (int k = 0; k < 32; ++k) s += partial[k * 64 + c];
  out[c] = s / (float)n;
}

extern "C" void kernel_launch(void* const* d_in, const int* in_sizes, int n_in,
                              void* d_out, int out_size, void* d_ws, size_t ws_size,
                              hipStream_t stream) {
  const float* pose = (const float*)d_in[0];
  const float* w_pos = (const float*)d_in[1];
  const float* b_pos = (const float*)d_in[2];
  const float* w_fc  = (const float*)d_in[3];
  const float* b_fc  = (const float*)d_in[4];
  const float* w_g1  = (const float*)d_in[5];
  const float* b_g1  = (const float*)d_in[6];
  const float* w_g2  = (const float*)d_in[7];
  const float* b_g2  = (const float*)d_in[8];
  const float* w_g3  = (const float*)d_in[9];
  const float* b_g3  = (const float*)d_in[10];
  const int*   edges = (const int*)d_in[11];

  const int n = in_sizes[0] / 64;   // N_NODES
  const int E = in_sizes[11] / 2;   // N_EDGES
  const int* rows = edges;
  const int* cols = edges + E;
  const int NB = (n + 511) >> 9;

  char* p = (char*)d_ws;
  auto alloc = [&](size_t bytes) { char* q = p; p += (bytes + 255) & ~(size_t)255; return q; };
  int*   off     = (int*)  alloc((size_t)(n + 1) * 4);
  int*   btot    = (int*)  alloc(256 * 4);
  int*   bbase   = (int*)  alloc(257 * 4);
  int*   gcur    = (int*)  alloc(256 * 4);
  float* dis     = (float*)alloc((size_t)n * 4);
  float* partial = (float*)alloc(32 * 64 * 4);
  u16* wp_pos_h = (u16*)alloc(2 * 8 * 64 * 8 * 2);
  u16* wp_pos_l = (u16*)alloc(2 * 8 * 64 * 8 * 2);
  u16* wp_fc_h  = (u16*)alloc(4 * 8 * 64 * 8 * 2);
  u16* wp_fc_l  = (u16*)alloc(4 * 8 * 64 * 8 * 2);
  u16* wp_g1_h  = (u16*)alloc(4 * 8 * 64 * 8 * 2);
  u16* wp_g1_l  = (u16*)alloc(4 * 8 * 64 * 8 * 2);
  u16* wp_g2_h  = (u16*)alloc(4 * 8 * 64 * 8 * 2);
  u16* wp_g2_l  = (u16*)alloc(4 * 8 * 64 * 8 * 2);
  u16* wp_g3_h  = (u16*)alloc(4 * 4 * 64 * 8 * 2);
  u16* wp_g3_l  = (u16*)alloc(4 * 4 * 64 * 8 * 2);
  int*   csr     = (int*)  alloc((size_t)E * 4);
  u16*   bufAb   = (u16*)  alloc((size_t)n * 128 * 2);   // bf16 hs (gather operand)
  float* bufB    = (float*)alloc((size_t)n * 128 * 4);   // f32 GEMM input / gather output
  // tmp (E int2, 12.8 MB) aliases bufAb (25.6 MB): consumed by bucket_csr before conv1 GEMM
  int2*  tmp     = (int2*)bufAb;

  const int eb4k        = (E + 4095) / 4096;
  const int gemm_blocks = (n + 63) / 64;
  const int g_blocks    = (n + 15) / 16;

  // ---- weight packs ----
  pack_w<<<(1024 + 255) / 256, 256, 0, stream>>>(w_pos, wp_pos_h, wp_pos_l, 64, 128);
  pack_w<<<(2048 + 255) / 256, 256, 0, stream>>>(w_fc,  wp_fc_h,  wp_fc_l,  128, 128);
  pack_w<<<(2048 + 255) / 256, 256, 0, stream>>>(w_g1,  wp_g1_h,  wp_g1_l,  128, 128);
  pack_w<<<(2048 + 255) / 256, 256, 0, stream>>>(w_g2,  wp_g2_h,  wp_g2_l,  128, 128);
  pack_w<<<(1024 + 255) / 256, 256, 0, stream>>>(w_g3,  wp_g3_h,  wp_g3_l,  128, 64);

  // ---- CSR build ----
  hipMemsetAsync(btot, 0, 256 * 4, stream);
  hipMemsetAsync(gcur, 0, 256 * 4, stream);
  hipMemsetAsync(partial, 0, 32 * 64 * 4, stream);
  bucket_cnt<<<eb4k, 256, 0, stream>>>(cols, btot, E, NB);
  scan_buckets<<<1, 256, 0, stream>>>(btot, bbase, NB);
  bin_pass<<<eb4k, 256, 0, stream>>>(rows, cols, bbase, gcur, tmp, E, NB);
  bucket_csr<<<NB, 256, 0, stream>>>(tmp, bbase, off, dis, csr, n, NB);

  // ---- refine (fused pair): pose -> bufB (f32) ----
  refine_fused<<<gemm_blocks, 256, 0, stream>>>(
      pose, wp_pos_h, wp_pos_l, b_pos, wp_fc_h, wp_fc_l, b_fc, bufB, n);

  // ---- conv1 ----
  gemm_mfma<128, 128, false, true, false, true><<<gemm_blocks, 256, 0, stream>>>(
      bufB, wp_g1_h, wp_g1_l, nullptr, dis, bufAb, n);
  gather_bf128<<<g_blocks, 256, 0, stream>>>(csr, off, bufAb, dis, b_g1, bufB, n);

  // ---- conv2 ----
  gemm_mfma<128, 128, false, true, false, true><<<gemm_blocks, 256, 0, stream>>>(
      bufB, wp_g2_h, wp_g2_l, nullptr, dis, bufAb, n);
  gather_bf128<<<g_blocks, 256, 0, stream>>>(csr, off, bufAb, dis, b_g2, bufB, n);

  // ---- conv3 + mean ----
  gemm_mfma<128, 64, false, true, false, true><<<gemm_blocks, 256, 0, stream>>>(
      bufB, wp_g3_h, wp_g3_l, nullptr, dis, bufAb, n);
  gather_mean_part<<<g_blocks, 256, 0, stream>>>(csr, off, bufAb, dis, b_g3, partial, n);
  mean_finish<<<1, 64, 0, stream>>>(partial, (float*)d_out, n);
}

// Round 9
// 320.081 us; speedup vs baseline: 22.5276x; 1.0963x over previous
//
#include <hip/hip_runtime.h>

#define SLOPE 0.01f

typedef __attribute__((ext_vector_type(8))) short short8;
typedef __attribute__((ext_vector_type(4))) float f32x4;
typedef unsigned short u16;
typedef unsigned int u32;

__device__ __forceinline__ float lrelu(float v) { return v >= 0.0f ? v : SLOPE * v; }

__device__ __forceinline__ u16 f2bf(float f) {
  u32 u = __float_as_uint(f);
  return (u16)((u + 0x7FFF + ((u >> 16) & 1)) >> 16);
}
__device__ __forceinline__ float bf2f(u16 h) {
  return __uint_as_float(((u32)h) << 16);
}
__device__ __forceinline__ float bflo(u32 u) { return __uint_as_float(u << 16); }
__device__ __forceinline__ float bfhi(u32 u) { return __uint_as_float(u & 0xffff0000u); }
__device__ __forceinline__ u32 packbf(float a, float b) {
  return ((u32)f2bf(b) << 16) | (u32)f2bf(a);
}

// ---------------- CSR: bucket totals (512 cols per bucket) ----------------
__global__ __launch_bounds__(256) void bucket_cnt(const int* __restrict__ cols,
                                                  int* __restrict__ btot, int E, int NB) {
  __shared__ int h[256];
  const int t = threadIdx.x;
  const int e0 = blockIdx.x * 4096;
  const int end = min(e0 + 4096, E);
  h[t] = 0;
  __syncthreads();
  for (int i = e0 + t; i < end; i += 256) atomicAdd(&h[cols[i] >> 9], 1);
  __syncthreads();
  if (t < NB && h[t]) atomicAdd(&btot[t], h[t]);
}

__global__ __launch_bounds__(256) void scan_buckets(const int* __restrict__ btot,
                                                    int* __restrict__ bbase, int NB) {
  __shared__ int s[256];
  const int t = threadIdx.x;
  int v = (t < NB) ? btot[t] : 0;
  s[t] = v;
  __syncthreads();
  for (int d = 1; d < 256; d <<= 1) {
    int u = (t >= d) ? s[t - d] : 0;
    __syncthreads();
    s[t] += u;
    __syncthreads();
  }
  bbase[t] = s[t] - v;
}

// ---------------- CSR fill pass A: LDS bucket-binning ----------------
__global__ __launch_bounds__(256) void bin_pass(const int* __restrict__ rows,
                                                const int* __restrict__ cols,
                                                const int* __restrict__ bbase,
                                                int* __restrict__ gcur,
                                                int2* __restrict__ tmp,
                                                int E, int NB) {
  __shared__ int hist[256];
  __shared__ int scanbuf[256];
  __shared__ int lstart[256];
  __shared__ int lcur[256];
  __shared__ int gbase[256];
  __shared__ int2 stage[4096];
  const int t = threadIdx.x;
  const int e0 = blockIdx.x * 4096;
  const int cnt = min(4096, E - e0);

  hist[t] = 0;
  __syncthreads();

  int ec[16], er[16];
  int m = 0;
  for (int i = t; i < cnt; i += 256) {
    int c = cols[e0 + i], r = rows[e0 + i];
    ec[m] = c; er[m] = r; ++m;
    atomicAdd(&hist[c >> 9], 1);
  }
  __syncthreads();

  int v = hist[t];
  scanbuf[t] = v;
  __syncthreads();
  for (int d = 1; d < 256; d <<= 1) {
    int u = (t >= d) ? scanbuf[t - d] : 0;
    __syncthreads();
    scanbuf[t] += u;
    __syncthreads();
  }
  lstart[t] = scanbuf[t] - v;
  lcur[t] = 0;
  __syncthreads();

  for (int k = 0; k < m; ++k) {
    int b = ec[k] >> 9;
    int p = lstart[b] + atomicAdd(&lcur[b], 1);
    stage[p] = make_int2(ec[k], er[k]);
  }
  __syncthreads();

  if (t < NB && hist[t] > 0) {
    gbase[t] = bbase[t] + atomicAdd(&gcur[t], hist[t]);
  }
  __syncthreads();

  for (int i = t; i < cnt; i += 256) {
    int2 pr = stage[i];
    int b = pr.x >> 9;
    tmp[gbase[b] + (i - lstart[b])] = pr;
  }
}

// ---------------- CSR pass B: per-bucket hist + scan + scatter + flush ----------------
__global__ __launch_bounds__(256) void bucket_csr(const int2* __restrict__ tmp,
                                                  const int* __restrict__ bbase,
                                                  int* __restrict__ off,
                                                  float* __restrict__ dis,
                                                  int* __restrict__ csr, int n, int NB) {
  const int b = blockIdx.x;
  const int c0 = b << 9;
  const int ncols = min(512, n - c0);
  __shared__ int hist[512];
  __shared__ int scanbuf[256];
  __shared__ int lofs[513];
  __shared__ int lcur[512];
  __shared__ int img[12288];
  const int t = threadIdx.x;
  const int base = bbase[b];
  const int bcnt = bbase[b + 1] - base;

  for (int i = t; i < 512; i += 256) { hist[i] = 0; lcur[i] = 0; }
  __syncthreads();
  for (int i = t; i < bcnt; i += 256) {
    int2 p = tmp[base + i];
    atomicAdd(&hist[p.x - c0], 1);
  }
  __syncthreads();

  int a0 = hist[2 * t], a1 = hist[2 * t + 1];
  int v = a0 + a1;
  scanbuf[t] = v;
  __syncthreads();
  for (int d = 1; d < 256; d <<= 1) {
    int u = (t >= d) ? scanbuf[t - d] : 0;
    __syncthreads();
    scanbuf[t] += u;
    __syncthreads();
  }
  int ex = scanbuf[t] - v;
  lofs[2 * t] = ex;
  lofs[2 * t + 1] = ex + a0;
  __syncthreads();

  for (int i = t; i < ncols; i += 256) {
    off[c0 + i] = base + lofs[i];
    dis[c0 + i] = rsqrtf((float)hist[i] + 1.0f);
  }
  if (b == NB - 1 && t == 0) off[n] = base + bcnt;

  if (bcnt <= 12288) {
    for (int i = t; i < bcnt; i += 256) {
      int2 p = tmp[base + i];
      int lc = p.x - c0;
      int pos = atomicAdd(&lcur[lc], 1);
      img[lofs[lc] + pos] = p.y;
    }
    __syncthreads();
    for (int i = t; i < bcnt; i += 256) csr[base + i] = img[i];
  } else {
    for (int i = t; i < bcnt; i += 256) {
      int2 p = tmp[base + i];
      int lc = p.x - c0;
      int pos = atomicAdd(&lcur[lc], 1);
      csr[base + lofs[lc] + pos] = p.y;
    }
  }
}

// ---------------- one-shot W pack (all 5 weights), fragment-ordered bf16 hi/lo ----------------
__global__ __launch_bounds__(256) void pack_all(
    const float* __restrict__ W0, const float* __restrict__ W1, const float* __restrict__ W2,
    const float* __restrict__ W3, const float* __restrict__ W4,
    u16* __restrict__ H0, u16* __restrict__ L0, u16* __restrict__ H1, u16* __restrict__ L1,
    u16* __restrict__ H2, u16* __restrict__ L2, u16* __restrict__ H3, u16* __restrict__ L3,
    u16* __restrict__ H4, u16* __restrict__ L4)
{
  int t = blockIdx.x * 256 + threadIdx.x;     // 8192 frags total
  const float* W; u16* hi; u16* lo; int K, C;
  if (t < 1024)      { W = W0; hi = H0; lo = L0; K = 64;  C = 128; }
  else if (t < 3072) { W = W1; hi = H1; lo = L1; K = 128; C = 128; t -= 1024; }
  else if (t < 5120) { W = W2; hi = H2; lo = L2; K = 128; C = 128; t -= 3072; }
  else if (t < 7168) { W = W3; hi = H3; lo = L3; K = 128; C = 128; t -= 5120; }
  else               { W = W4; hi = H4; lo = L4; K = 128; C = 64;  t -= 7168; }
  const int KS = K / 32;
  int l = t & 63;
  int rest = t >> 6;
  int ks = rest % KS;
  int ct = rest / KS;
  int k0 = ks * 32 + (l >> 4) * 8;
  int c  = ct * 16 + (l & 15);
  short8 hv, lv;
  #pragma unroll
  for (int b = 0; b < 8; ++b) {
    float v = W[(size_t)(k0 + b) * C + c];
    u16 h = f2bf(v);
    hv[b] = (short)h;
    lv[b] = (short)f2bf(v - bf2f(h));
  }
  ((short8*)hi)[t] = hv;
  ((short8*)lo)[t] = lv;
}

// ---------------- conv GEMM: bf16 in -> bf16 out, y = (x@W)*dis; 2-term W split ----------------
template<int K, int C>
__global__ __launch_bounds__(256) void gemm_conv(
    const u16* __restrict__ x,
    const u16* __restrict__ whi, const u16* __restrict__ wlo,
    const float* __restrict__ rowscale, u16* __restrict__ y, int n)
{
  constexpr int NC = C / 16;
  constexpr int KS = K / 32;
  const int t = threadIdx.x;
  const int w = t >> 6;
  const int lane = t & 63;
  const int row_base = blockIdx.x * 64 + w * 16;
  const int arow_raw = row_base + (lane & 15);
  const int arow = (arow_raw < n) ? arow_raw : 0;
  const int asub = (lane >> 4) * 8;
  const u16* xrow = x + (size_t)arow * K + asub;

  f32x4 acc[NC];
  #pragma unroll
  for (int ct = 0; ct < NC; ++ct) acc[ct] = (f32x4){0.f, 0.f, 0.f, 0.f};

  const short8* WH = (const short8*)whi;
  const short8* WL = (const short8*)wlo;

  #pragma unroll
  for (int ks = 0; ks < KS; ++ks) {
    short8 ah = *(const short8*)(xrow + ks * 32);   // exact bf16 input: no lo term
    #pragma unroll
    for (int ct = 0; ct < NC; ++ct) {
      short8 bh = WH[(ct * KS + ks) * 64 + lane];
      short8 bl = WL[(ct * KS + ks) * 64 + lane];
      acc[ct] = __builtin_amdgcn_mfma_f32_16x16x32_bf16(ah, bh, acc[ct], 0, 0, 0);
      acc[ct] = __builtin_amdgcn_mfma_f32_16x16x32_bf16(ah, bl, acc[ct], 0, 0, 0);
    }
  }

  const int colb = lane & 15;
  const int rsub = (lane >> 4) * 4;
  #pragma unroll
  for (int r = 0; r < 4; ++r) {
    int row = row_base + rsub + r;
    if (row >= n) continue;
    float sc = rowscale[row];
    #pragma unroll
    for (int ct = 0; ct < NC; ++ct)
      y[(size_t)row * C + ct * 16 + colb] = f2bf(acc[ct][r] * sc);
  }
}

// ---------------- fused refine: x2 = lrelu(pose@Wpos+b)@Wfc + bfc -> bf16 ----------------
__global__ __launch_bounds__(256) void refine_fused(
    const float* __restrict__ pose,
    const u16* __restrict__ wph, const u16* __restrict__ wpl,
    const float* __restrict__ b_pos,
    const u16* __restrict__ wfh, const u16* __restrict__ wfl,
    const float* __restrict__ b_fc,
    u16* __restrict__ y, int n)
{
  __shared__ float x1s[4][16][132];
  const int t = threadIdx.x;
  const int w = t >> 6;
  const int lane = t & 63;
  const int row_base = blockIdx.x * 64 + w * 16;
  const int colb = lane & 15;
  const int rsub = (lane >> 4) * 4;
  const int asub = (lane >> 4) * 8;

  {
    const int arow_raw = row_base + (lane & 15);
    const int arow = (arow_raw < n) ? arow_raw : 0;
    const float* xrow = pose + (size_t)arow * 64 + asub;
    f32x4 acc[8];
    #pragma unroll
    for (int ct = 0; ct < 8; ++ct) acc[ct] = (f32x4){0.f, 0.f, 0.f, 0.f};
    const short8* WH = (const short8*)wph;
    const short8* WL = (const short8*)wpl;
    #pragma unroll
    for (int ks = 0; ks < 2; ++ks) {
      float4 v0 = *(const float4*)(xrow + ks * 32);
      float4 v1 = *(const float4*)(xrow + ks * 32 + 4);
      float xv[8] = {v0.x, v0.y, v0.z, v0.w, v1.x, v1.y, v1.z, v1.w};
      short8 ah, al;
      #pragma unroll
      for (int b = 0; b < 8; ++b) {
        u16 h = f2bf(xv[b]);
        ah[b] = (short)h;
        al[b] = (short)f2bf(xv[b] - bf2f(h));
      }
      #pragma unroll
      for (int ct = 0; ct < 8; ++ct) {
        short8 bh = WH[(ct * 2 + ks) * 64 + lane];
        short8 bl = WL[(ct * 2 + ks) * 64 + lane];
        acc[ct] = __builtin_amdgcn_mfma_f32_16x16x32_bf16(ah, bh, acc[ct], 0, 0, 0);
        acc[ct] = __builtin_amdgcn_mfma_f32_16x16x32_bf16(ah, bl, acc[ct], 0, 0, 0);
        acc[ct] = __builtin_amdgcn_mfma_f32_16x16x32_bf16(al, bh, acc[ct], 0, 0, 0);
      }
    }
    #pragma unroll
    for (int ct = 0; ct < 8; ++ct) {
      float bb = b_pos[ct * 16 + colb];
      #pragma unroll
      for (int r = 0; r < 4; ++r)
        x1s[w][rsub + r][ct * 16 + colb] = lrelu(acc[ct][r] + bb);
    }
  }
  __syncthreads();

  {
    f32x4 acc[8];
    #pragma unroll
    for (int ct = 0; ct < 8; ++ct) acc[ct] = (f32x4){0.f, 0.f, 0.f, 0.f};
    const short8* WH = (const short8*)wfh;
    const short8* WL = (const short8*)wfl;
    const float* x1row = &x1s[w][lane & 15][0];
    #pragma unroll
    for (int ks = 0; ks < 4; ++ks) {
      float4 v0 = *(const float4*)(x1row + ks * 32 + asub);
      float4 v1 = *(const float4*)(x1row + ks * 32 + asub + 4);
      float xv[8] = {v0.x, v0.y, v0.z, v0.w, v1.x, v1.y, v1.z, v1.w};
      short8 ah, al;
      #pragma unroll
      for (int b = 0; b < 8; ++b) {
        u16 h = f2bf(xv[b]);
        ah[b] = (short)h;
        al[b] = (short)f2bf(xv[b] - bf2f(h));
      }
      #pragma unroll
      for (int ct = 0; ct < 8; ++ct) {
        short8 bh = WH[(ct * 4 + ks) * 64 + lane];
        short8 bl = WL[(ct * 4 + ks) * 64 + lane];
        acc[ct] = __builtin_amdgcn_mfma_f32_16x16x32_bf16(ah, bh, acc[ct], 0, 0, 0);
        acc[ct] = __builtin_amdgcn_mfma_f32_16x16x32_bf16(ah, bl, acc[ct], 0, 0, 0);
        acc[ct] = __builtin_amdgcn_mfma_f32_16x16x32_bf16(al, bh, acc[ct], 0, 0, 0);
      }
    }
    #pragma unroll
    for (int r = 0; r < 4; ++r) {
      int row = row_base + rsub + r;
      if (row >= n) continue;
      #pragma unroll
      for (int ct = 0; ct < 8; ++ct)
        y[(size_t)row * 128 + ct * 16 + colb] = f2bf(acc[ct][r] + b_fc[ct * 16 + colb]);
    }
  }
}

// ---------------- bf16 gather bursts ----------------
template<int U>
__device__ __forceinline__ void gulp128b(const uint4* __restrict__ hsv, int idx, int j,
                                         int l, float* acc) {
  uint4 a[U];
  #pragma unroll
  for (int u = 0; u < U; ++u) {
    int r = __shfl(idx, j + u, 16);
    a[u] = hsv[(size_t)r * 16 + l];
  }
  #pragma unroll
  for (int u = 0; u < U; ++u) {
    acc[0] += bflo(a[u].x); acc[1] += bfhi(a[u].x);
    acc[2] += bflo(a[u].y); acc[3] += bfhi(a[u].y);
    acc[4] += bflo(a[u].z); acc[5] += bfhi(a[u].z);
    acc[6] += bflo(a[u].w); acc[7] += bfhi(a[u].w);
  }
}

template<int U>
__device__ __forceinline__ void gulp64b(const uint2* __restrict__ hsv, int idx, int j,
                                        int l, float* acc) {
  uint2 a[U];
  #pragma unroll
  for (int u = 0; u < U; ++u) {
    int r = __shfl(idx, j + u, 16);
    a[u] = hsv[(size_t)r * 16 + l];
  }
  #pragma unroll
  for (int u = 0; u < U; ++u) {
    acc[0] += bflo(a[u].x); acc[1] += bfhi(a[u].x);
    acc[2] += bflo(a[u].y); acc[3] += bfhi(a[u].y);
  }
}

// ---------------- gather (C=128, bf16 in/out): 16 lanes/node ----------------
__global__ __launch_bounds__(256) void gather_bf128(
    const int* __restrict__ csr, const int* __restrict__ off,
    const u16* __restrict__ hs, const float* __restrict__ dis,
    const float* __restrict__ bias, u16* __restrict__ y, int n)
{
  const int t = threadIdx.x;
  const int l = t & 15;
  const int node = blockIdx.x * 16 + (t >> 4);
  if (node >= n) return;
  const int o = off[node];
  const int d = off[node + 1] - o;
  const float dd = dis[node];
  const uint4* hsv = (const uint4*)hs;

  uint4 hv = hsv[(size_t)node * 16 + l];
  float acc[8];
  acc[0] = bflo(hv.x); acc[1] = bfhi(hv.x);
  acc[2] = bflo(hv.y); acc[3] = bfhi(hv.y);
  acc[4] = bflo(hv.z); acc[5] = bfhi(hv.z);
  acc[6] = bflo(hv.w); acc[7] = bfhi(hv.w);

  for (int base = 0; base < d; base += 16) {
    const int batch = min(d - base, 16);
    int idx = (l < batch) ? csr[o + base + l] : 0;
    int j = 0;
    for (; j + 8 <= batch; j += 8) gulp128b<8>(hsv, idx, j, l, acc);
    if (j + 4 <= batch) { gulp128b<4>(hsv, idx, j, l, acc); j += 4; }
    for (; j < batch; ++j) gulp128b<1>(hsv, idx, j, l, acc);
  }

  float4 b0 = *(const float4*)(bias + l * 8);
  float4 b1 = *(const float4*)(bias + l * 8 + 4);
  float o0 = lrelu(acc[0] * dd + b0.x), o1 = lrelu(acc[1] * dd + b0.y);
  float o2 = lrelu(acc[2] * dd + b0.z), o3 = lrelu(acc[3] * dd + b0.w);
  float o4 = lrelu(acc[4] * dd + b1.x), o5 = lrelu(acc[5] * dd + b1.y);
  float o6 = lrelu(acc[6] * dd + b1.z), o7 = lrelu(acc[7] * dd + b1.w);
  uint4 wv;
  wv.x = packbf(o0, o1); wv.y = packbf(o2, o3);
  wv.z = packbf(o4, o5); wv.w = packbf(o6, o7);
  *(uint4*)(y + (size_t)node * 128 + l * 8) = wv;
}

// ---------------- conv3: gather (C=64 bf16) + finalize + block partial sums ----------------
__global__ __launch_bounds__(256) void gather_mean_part(
    const int* __restrict__ csr, const int* __restrict__ off,
    const u16* __restrict__ hs, const float* __restrict__ dis,
    const float* __restrict__ bias, float* __restrict__ partial, int n)
{
  const int t = threadIdx.x;
  const int l = t & 15;
  const int node = blockIdx.x * 16 + (t >> 4);
  float4 b4 = *(const float4*)(bias + l * 4);
  float4 val = make_float4(0.f, 0.f, 0.f, 0.f);

  if (node < n) {
    const int o = off[node];
    const int d = off[node + 1] - o;
    const float dd = dis[node];
    const uint2* hsv = (const uint2*)hs;
    uint2 hv = hsv[(size_t)node * 16 + l];
    float acc[4];
    acc[0] = bflo(hv.x); acc[1] = bfhi(hv.x);
    acc[2] = bflo(hv.y); acc[3] = bfhi(hv.y);
    for (int base = 0; base < d; base += 16) {
      const int batch = min(d - base, 16);
      int idx = (l < batch) ? csr[o + base + l] : 0;
      int j = 0;
      for (; j + 8 <= batch; j += 8) gulp64b<8>(hsv, idx, j, l, acc);
      if (j + 4 <= batch) { gulp64b<4>(hsv, idx, j, l, acc); j += 4; }
      for (; j < batch; ++j) gulp64b<1>(hsv, idx, j, l, acc);
    }
    val.x = lrelu(acc[0] * dd + b4.x);
    val.y = lrelu(acc[1] * dd + b4.y);
    val.z = lrelu(acc[2] * dd + b4.z);
    val.w = lrelu(acc[3] * dd + b4.w);
  }

  __shared__ float4 s[256];
  s[t] = val;
  __syncthreads();
  for (int offst = 128; offst >= 16; offst >>= 1) {
    if (t < offst) {
      s[t].x += s[t + offst].x; s[t].y += s[t + offst].y;
      s[t].z += s[t + offst].z; s[t].w += s[t + offst].w;
    }
    __syncthreads();
  }
  if (t < 16) {
    float* slot = partial + (size_t)(blockIdx.x & 31) * 64;
    atomicAdd(slot + t * 4 + 0, s[t].x);
    atomicAdd(slot + t * 4 + 1, s[t].y);
    atomicAdd(slot + t * 4 + 2, s[t].z);
    atomicAdd(slot + t * 4 + 3, s[t].w);
  }
}

__global__ __launch_bounds__(64) void mean_finish(const float* __restrict__ partial,
                                                  float* __restrict__ out, int n) {
  const int c = threadIdx.x;
  float s = 0.f;
  #pragma unroll
  for (int k = 0; k < 32; ++k) s += partial[k * 64 + c];
  out[c] = s / (float)n;
}

extern "C" void kernel_launch(void* const* d_in, const int* in_sizes, int n_in,
                              void* d_out, int out_size, void* d_ws, size_t ws_size,
                              hipStream_t stream) {
  const float* pose = (const float*)d_in[0];
  const float* w_pos = (const float*)d_in[1];
  const float* b_pos = (const float*)d_in[2];
  const float* w_fc  = (const float*)d_in[3];
  const float* b_fc  = (const float*)d_in[4];
  const float* w_g1  = (const float*)d_in[5];
  const float* b_g1  = (const float*)d_in[6];
  const float* w_g2  = (const float*)d_in[7];
  const float* b_g2  = (const float*)d_in[8];
  const float* w_g3  = (const float*)d_in[9];
  const float* b_g3  = (const float*)d_in[10];
  const int*   edges = (const int*)d_in[11];

  const int n = in_sizes[0] / 64;   // N_NODES
  const int E = in_sizes[11] / 2;   // N_EDGES
  const int* rows = edges;
  const int* cols = edges + E;
  const int NB = (n + 511) >> 9;

  char* p = (char*)d_ws;
  auto alloc = [&](size_t bytes) { char* q = p; p += (bytes + 255) & ~(size_t)255; return q; };
  int*   off     = (int*)  alloc((size_t)(n + 1) * 4);
  // contiguous zero-init region: btot(256) | gcur(256) | partial(2048)
  int*   misc    = (int*)  alloc((256 + 256 + 2048) * 4);
  int*   btot    = misc;
  int*   gcur    = misc + 256;
  float* partial = (float*)(misc + 512);
  int*   bbase   = (int*)  alloc(257 * 4);
  float* dis     = (float*)alloc((size_t)n * 4);
  u16* wp_pos_h = (u16*)alloc(1024 * 16);
  u16* wp_pos_l = (u16*)alloc(1024 * 16);
  u16* wp_fc_h  = (u16*)alloc(2048 * 16);
  u16* wp_fc_l  = (u16*)alloc(2048 * 16);
  u16* wp_g1_h  = (u16*)alloc(2048 * 16);
  u16* wp_g1_l  = (u16*)alloc(2048 * 16);
  u16* wp_g2_h  = (u16*)alloc(2048 * 16);
  u16* wp_g2_l  = (u16*)alloc(2048 * 16);
  u16* wp_g3_h  = (u16*)alloc(1024 * 16);
  u16* wp_g3_l  = (u16*)alloc(1024 * 16);
  int*   csr     = (int*)  alloc((size_t)E * 4);
  u16*   bufA    = (u16*)  alloc((size_t)n * 128 * 2);
  u16*   bufB    = (u16*)  alloc((size_t)n * 128 * 2);
  // tmp (E int2, 12.8 MB) aliases bufA+bufB region start: consumed before conv1 GEMM writes
  int2*  tmp     = (int2*)bufA;

  const int eb4k        = (E + 4095) / 4096;
  const int gemm_blocks = (n + 63) / 64;
  const int g_blocks    = (n + 15) / 16;

  // ---- weight packs (one launch) ----
  pack_all<<<32, 256, 0, stream>>>(w_pos, w_fc, w_g1, w_g2, w_g3,
      wp_pos_h, wp_pos_l, wp_fc_h, wp_fc_l, wp_g1_h, wp_g1_l,
      wp_g2_h, wp_g2_l, wp_g3_h, wp_g3_l);

  // ---- CSR build ----
  hipMemsetAsync(misc, 0, (256 + 256 + 2048) * 4, stream);
  bucket_cnt<<<eb4k, 256, 0, stream>>>(cols, btot, E, NB);
  scan_buckets<<<1, 256, 0, stream>>>(btot, bbase, NB);
  bin_pass<<<eb4k, 256, 0, stream>>>(rows, cols, bbase, gcur, tmp, E, NB);
  bucket_csr<<<NB, 256, 0, stream>>>(tmp, bbase, off, dis, csr, n, NB);

  // ---- refine (fused pair): pose -> bufB (bf16) ----
  refine_fused<<<gemm_blocks, 256, 0, stream>>>(
      pose, wp_pos_h, wp_pos_l, b_pos, wp_fc_h, wp_fc_l, b_fc, bufB, n);

  // ---- conv1 ----
  gemm_conv<128, 128><<<gemm_blocks, 256, 0, stream>>>(bufB, wp_g1_h, wp_g1_l, dis, bufA, n);
  gather_bf128<<<g_blocks, 256, 0, stream>>>(csr, off, bufA, dis, b_g1, bufB, n);

  // ---- conv2 ----
  gemm_conv<128, 128><<<gemm_blocks, 256, 0, stream>>>(bufB, wp_g2_h, wp_g2_l, dis, bufA, n);
  gather_bf128<<<g_blocks, 256, 0, stream>>>(csr, off, bufA, dis, b_g2, bufB, n);

  // ---- conv3 + mean ----
  gemm_conv<128, 64><<<gemm_blocks, 256, 0, stream>>>(bufB, wp_g3_h, wp_g3_l, dis, bufA, n);
  gather_mean_part<<<g_blocks, 256, 0, stream>>>(csr, off, bufA, dis, b_g3, partial, n);
  mean_finish<<<1, 64, 0, stream>>>(partial, (float*)d_out, n);
}